// Round 1
// baseline (382.729 us; speedup 1.0000x reference)
//
#include <hip/hip_runtime.h>

#define Bsz 8
#define Tsz 2048
#define Csz 1024
#define HSsz 64
#define NQ 192   // 3*hs

// ---------------- transpose qkv_w [192][1024] -> wT [1024][192] ----------------
__global__ __launch_bounds__(256) void k_transpose_w(const float* __restrict__ w,
                                                     float* __restrict__ wT) {
    int idx = blockIdx.x * 256 + threadIdx.x;   // 196608 threads
    int c = idx & 1023;                          // fast -> coalesced read of w row
    int j = idx >> 10;                           // 0..191
    wT[c * NQ + j] = w[j * Csz + c];
}

// ------------- reduce proj_w over heads: w2t[d][c] = sum_h proj_w[c][h*64+d] -------------
__global__ __launch_bounds__(256) void k_w2t(const float* __restrict__ pw,
                                             float* __restrict__ w2t) {
    int idx = blockIdx.x * 256 + threadIdx.x;   // 65536 threads
    int d = idx & 63;                            // fast -> coalesced reads
    int c = idx >> 6;                            // 0..1023
    float s = 0.f;
#pragma unroll
    for (int hh = 0; hh < 16; ++hh) s += pw[c * Csz + hh * HSsz + d];
    w2t[d * Csz + c] = s;
}

// ---------------- qkv = ids @ qkv_w^T + b : [16384 x 1024] x [1024 x 192] ----------------
// block: 256 thr = jt(64) x rt(4); 64 rows per block; 16 rows per thread, 3 j's per thread
__global__ __launch_bounds__(256) void k_qkv(const float* __restrict__ ids,
                                             const float* __restrict__ wT,
                                             const float* __restrict__ bias,
                                             float* __restrict__ qkv) {
    __shared__ float at[32 * 68];   // ids chunk transposed: [cc][row], pad 68
    const int tid = threadIdx.x;
    const int jt = tid & 63;
    const int rt = tid >> 6;               // 0..3 -> rows rt*16..rt*16+15
    const int bt0 = blockIdx.x * 64;

    float acc[3][16];
    const float b0 = bias[jt], b1 = bias[jt + 64], b2 = bias[jt + 128];
#pragma unroll
    for (int r = 0; r < 16; ++r) { acc[0][r] = b0; acc[1][r] = b1; acc[2][r] = b2; }

    for (int ch = 0; ch < 32; ++ch) {
        const int c0 = ch * 32;
        __syncthreads();
#pragma unroll
        for (int kk = 0; kk < 8; ++kk) {
            int idx = kk * 256 + tid;
            int row = idx >> 5, cc = idx & 31;          // coalesced global read
            at[cc * 68 + row] = ids[(bt0 + row) * Csz + c0 + cc];
        }
        __syncthreads();
#pragma unroll 4
        for (int cc = 0; cc < 32; ++cc) {
            const float* wr = &wT[(c0 + cc) * NQ + jt];  // coalesced over lanes
            float w0 = wr[0], w1 = wr[64], w2 = wr[128];
            const float* ap = &at[cc * 68 + rt * 16];
            float av[16];
            *(float4*)&av[0]  = *(const float4*)(ap + 0);   // broadcast b128 reads
            *(float4*)&av[4]  = *(const float4*)(ap + 4);
            *(float4*)&av[8]  = *(const float4*)(ap + 8);
            *(float4*)&av[12] = *(const float4*)(ap + 12);
#pragma unroll
            for (int r = 0; r < 16; ++r) {
                acc[0][r] = fmaf(w0, av[r], acc[0][r]);
                acc[1][r] = fmaf(w1, av[r], acc[1][r]);
                acc[2][r] = fmaf(w2, av[r], acc[2][r]);
            }
        }
    }
#pragma unroll
    for (int m = 0; m < 3; ++m)
#pragma unroll
        for (int r = 0; r < 16; ++r)
            qkv[(bt0 + rt * 16 + r) * NQ + jt + 64 * m] = acc[m][r];
}

// ---------------- fused causal attention (no softmax) ----------------
// TM=32 query rows/block, SN=128 key rows/tile. 512 blocks, 256 threads.
// LDS: q[32][64], kv-union (kT [64][132] then v [128][64]), wei [32][128] = 58 KB
__global__ __launch_bounds__(256) void k_attn(const float* __restrict__ qkv,
                                              float* __restrict__ h) {
    __shared__ float q_lds[32 * 64];
    __shared__ float kvb[64 * 132];
    __shared__ float wei[32 * 128];

    const int tid = threadIdx.x;
    const int u = blockIdx.x;
    int b, i;   // heavy/light pairing: CU gets one i>=32 and one i<32 block
    if (u < 256) { b = u >> 5; i = 32 + (u & 31); }
    else         { int uu = u - 256; b = uu >> 5; i = 31 - (uu & 31); }

    const int base = b * Tsz;
    const int ns = (i * 32 + 31) / 128 + 1;     // # of 128-wide s-tiles

    // stage Q tile [32][64]
#pragma unroll
    for (int kk = 0; kk < 2; ++kk) {
        int idx = kk * 256 + tid;
        int row = idx >> 4, c4 = idx & 15;
        *(float4*)&q_lds[row * 64 + c4 * 4] =
            *(const float4*)&qkv[(base + i * 32 + row) * NQ + c4 * 4];
    }

    const int g5 = tid >> 5;       // 0..7
    const int l5 = tid & 31;       // 0..31
    const int wr0 = g5 * 4;        // wei/out rows: 4 per thread
    const int ws0 = l5 * 4;        // wei cols: 4 per thread
    const int d0 = l5 * 2;         // out dims: 2 per thread

    float acc[4][2];
#pragma unroll
    for (int m = 0; m < 4; ++m) { acc[m][0] = 0.f; acc[m][1] = 0.f; }

    for (int st = 0; st < ns; ++st) {
        __syncthreads();
        // stage K transposed: kT[d][s] stride 132
#pragma unroll
        for (int kk = 0; kk < 8; ++kk) {
            int idx = kk * 256 + tid;
            int srow = idx >> 4, c4 = idx & 15;
            float4 kx = *(const float4*)&qkv[(base + st * 128 + srow) * NQ + 64 + c4 * 4];
            kvb[(c4 * 4 + 0) * 132 + srow] = kx.x;
            kvb[(c4 * 4 + 1) * 132 + srow] = kx.y;
            kvb[(c4 * 4 + 2) * 132 + srow] = kx.z;
            kvb[(c4 * 4 + 3) * 132 + srow] = kx.w;
        }
        __syncthreads();
        // QK^T -> wei tile
        float dot[4][4];
#pragma unroll
        for (int m = 0; m < 4; ++m)
#pragma unroll
            for (int sj = 0; sj < 4; ++sj) dot[m][sj] = 0.f;
#pragma unroll 4
        for (int d4 = 0; d4 < 16; ++d4) {
            float qv[4][4];
#pragma unroll
            for (int m = 0; m < 4; ++m)
                *(float4*)&qv[m][0] = *(const float4*)&q_lds[(wr0 + m) * 64 + d4 * 4];
#pragma unroll
            for (int dd = 0; dd < 4; ++dd) {
                float4 k4 = *(const float4*)&kvb[(d4 * 4 + dd) * 132 + ws0];
#pragma unroll
                for (int m = 0; m < 4; ++m) {
                    dot[m][0] = fmaf(qv[m][dd], k4.x, dot[m][0]);
                    dot[m][1] = fmaf(qv[m][dd], k4.y, dot[m][1]);
                    dot[m][2] = fmaf(qv[m][dd], k4.z, dot[m][2]);
                    dot[m][3] = fmaf(qv[m][dd], k4.w, dot[m][3]);
                }
            }
        }
        const bool last = (st == ns - 1);
#pragma unroll
        for (int m = 0; m < 4; ++m) {
            const int tg = i * 32 + wr0 + m;
            float4 w4;
            float* wp = (float*)&w4;
#pragma unroll
            for (int sj = 0; sj < 4; ++sj) {
                int sg = st * 128 + ws0 + sj;
                wp[sj] = (last && sg > tg) ? 0.f : dot[m][sj];
            }
            *(float4*)&wei[(wr0 + m) * 128 + ws0] = w4;
        }
        __syncthreads();
        // stage V row-major [s][d] into same buffer
#pragma unroll
        for (int kk = 0; kk < 8; ++kk) {
            int idx = kk * 256 + tid;
            int srow = idx >> 4, c4 = idx & 15;
            *(float4*)&kvb[srow * 64 + c4 * 4] =
                *(const float4*)&qkv[(base + st * 128 + srow) * NQ + 128 + c4 * 4];
        }
        __syncthreads();
        // PV: acc += wei @ V
#pragma unroll 8
        for (int s4 = 0; s4 < 32; ++s4) {
            float wv[4][4];
#pragma unroll
            for (int m = 0; m < 4; ++m)
                *(float4*)&wv[m][0] = *(const float4*)&wei[(wr0 + m) * 128 + s4 * 4];
#pragma unroll
            for (int ss = 0; ss < 4; ++ss) {
                float2 v2 = *(const float2*)&kvb[(s4 * 4 + ss) * 64 + d0];
#pragma unroll
                for (int m = 0; m < 4; ++m) {
                    acc[m][0] = fmaf(wv[m][ss], v2.x, acc[m][0]);
                    acc[m][1] = fmaf(wv[m][ss], v2.y, acc[m][1]);
                }
            }
        }
    }
#pragma unroll
    for (int m = 0; m < 4; ++m) {
        float2 o; o.x = acc[m][0]; o.y = acc[m][1];
        *(float2*)&h[(base + i * 32 + wr0 + m) * HSsz + d0] = o;
    }
}

// ---------------- out = h @ W2^T + proj_b : [16384 x 64] x [64 x 1024] ----------------
// block: 256 thr, 16 bt rows; each thread owns 4 consecutive c for all 16 rows
__global__ __launch_bounds__(256) void k_proj(const float* __restrict__ h,
                                              const float* __restrict__ w2t,
                                              const float* __restrict__ pb,
                                              float* __restrict__ out) {
    __shared__ float hT[64 * 20];   // [d][row], pad 20 keeps b128 alignment
    const int tid = threadIdx.x;
    const int bt0 = blockIdx.x * 16;
#pragma unroll
    for (int kk = 0; kk < 4; ++kk) {
        int idx = kk * 256 + tid;
        int d = idx & 63, row = idx >> 6;            // coalesced global read
        hT[d * 20 + row] = h[(bt0 + row) * HSsz + d];
    }
    __syncthreads();
    const int c0 = tid * 4;
    const float4 pb4 = *(const float4*)&pb[c0];
    float a[16][4];
#pragma unroll
    for (int r = 0; r < 16; ++r) {
        a[r][0] = pb4.x; a[r][1] = pb4.y; a[r][2] = pb4.z; a[r][3] = pb4.w;
    }
#pragma unroll 4
    for (int d = 0; d < 64; ++d) {
        float4 w4 = *(const float4*)&w2t[d * Csz + c0];   // coalesced, L2-hot
        float hv[16];
        *(float4*)&hv[0]  = *(const float4*)&hT[d * 20 + 0];
        *(float4*)&hv[4]  = *(const float4*)&hT[d * 20 + 4];
        *(float4*)&hv[8]  = *(const float4*)&hT[d * 20 + 8];
        *(float4*)&hv[12] = *(const float4*)&hT[d * 20 + 12];
#pragma unroll
        for (int r = 0; r < 16; ++r) {
            a[r][0] = fmaf(hv[r], w4.x, a[r][0]);
            a[r][1] = fmaf(hv[r], w4.y, a[r][1]);
            a[r][2] = fmaf(hv[r], w4.z, a[r][2]);
            a[r][3] = fmaf(hv[r], w4.w, a[r][3]);
        }
    }
#pragma unroll
    for (int r = 0; r < 16; ++r) {
        float4 o; o.x = a[r][0]; o.y = a[r][1]; o.z = a[r][2]; o.w = a[r][3];
        *(float4*)&out[(bt0 + r) * Csz + c0] = o;
    }
}

extern "C" void kernel_launch(void* const* d_in, const int* in_sizes, int n_in,
                              void* d_out, int out_size, void* d_ws, size_t ws_size,
                              hipStream_t stream) {
    const float* ids    = (const float*)d_in[0];
    const float* qkv_w  = (const float*)d_in[1];
    const float* qkv_b  = (const float*)d_in[2];
    const float* proj_w = (const float*)d_in[3];
    const float* proj_b = (const float*)d_in[4];
    float* out = (float*)d_out;

    float* ws  = (float*)d_ws;
    float* qkv = ws;                           // 16384*192 f32
    float* h   = qkv + 16384 * NQ;             // 16384*64
    float* wT  = h + 16384 * HSsz;             // 1024*192
    float* w2t = wT + Csz * NQ;                // 64*1024   (~17.8 MB total)

    hipLaunchKernelGGL(k_transpose_w, dim3(768),  dim3(256), 0, stream, qkv_w, wT);
    hipLaunchKernelGGL(k_w2t,         dim3(256),  dim3(256), 0, stream, proj_w, w2t);
    hipLaunchKernelGGL(k_qkv,         dim3(256),  dim3(256), 0, stream, ids, wT, qkv_b, qkv);
    hipLaunchKernelGGL(k_attn,        dim3(512),  dim3(256), 0, stream, qkv, h);
    hipLaunchKernelGGL(k_proj,        dim3(1024), dim3(256), 0, stream, h, w2t, proj_b, out);
}

// Round 2
// 202.621 us; speedup vs baseline: 1.8889x; 1.8889x over previous
//
#include <hip/hip_runtime.h>

#define Bsz 8
#define Tsz 2048
#define Csz 1024
#define HSsz 64
#define NQ 192   // 3*hs

typedef __attribute__((ext_vector_type(8))) short short8v;
typedef __attribute__((ext_vector_type(4))) float f32x4;

// fp32 -> bf16 round-to-nearest-even
__device__ __forceinline__ unsigned int f2bf(float f) {
    union { float f; unsigned int u; } v; v.f = f;
    return (v.u + 0x7fffu + ((v.u >> 16) & 1u)) >> 16;
}

// ------------- reduce proj_w over heads: w2t[d][c] = sum_h proj_w[c][h*64+d] -------------
__global__ __launch_bounds__(256) void k_w2t(const float* __restrict__ pw,
                                             float* __restrict__ w2t) {
    int idx = blockIdx.x * 256 + threadIdx.x;   // 65536 threads
    int d = idx & 63;                            // fast -> coalesced reads
    int c = idx >> 6;                            // 0..1023
    float s = 0.f;
#pragma unroll
    for (int hh = 0; hh < 16; ++hh) s += pw[c * Csz + hh * HSsz + d];
    w2t[d * Csz + c] = s;
}

// ------------- pack qkv_w into per-lane MFMA B fragments, bf16 -------------
// layout: [ks 0..31][jt 0..11][lane 0..63][8 bf16]; value = qkv_w[jt*16+(l&15)][ks*32+(l>>4)*8+b]
__global__ __launch_bounds__(256) void k_packB(const float* __restrict__ w,
                                               unsigned short* __restrict__ wB) {
    int idx = blockIdx.x * 256 + threadIdx.x;   // 24576 threads = 12*32*64
    int l = idx & 63;
    int ksjt = idx >> 6;                         // ks*12 + jt
    int jt = ksjt % 12, ks = ksjt / 12;
    int j = jt * 16 + (l & 15);
    int k = ks * 32 + (l >> 4) * 8;
    const float* src = &w[j * Csz + k];
    float4 a = *(const float4*)src;
    float4 b = *(const float4*)(src + 4);
    unsigned int o0 = f2bf(a.x) | (f2bf(a.y) << 16);
    unsigned int o1 = f2bf(a.z) | (f2bf(a.w) << 16);
    unsigned int o2 = f2bf(b.x) | (f2bf(b.y) << 16);
    unsigned int o3 = f2bf(b.z) | (f2bf(b.w) << 16);
    uint4 o; o.x = o0; o.y = o1; o.z = o2; o.w = o3;
    *(uint4*)&wB[idx * 8] = o;                   // 16B coalesced store
}

// ---------------- qkv = ids @ qkv_w^T + b via bf16 MFMA ----------------
// block: 256 thr = 4 waves (2 row-waves x 2 col-waves); block tile 32 x 192; grid 512
__global__ __launch_bounds__(256) void k_qkv_mfma(const float* __restrict__ ids,
                                                  const unsigned short* __restrict__ wB,
                                                  const float* __restrict__ bias,
                                                  float* __restrict__ qkv) {
    const int tid = threadIdx.x;
    const int wv = tid >> 6;
    const int l  = tid & 63;
    const int wm = wv & 1, wn = wv >> 1;
    const int jt0 = wn * 6;

    const int arow = blockIdx.x * 32 + wm * 16 + (l & 15);
    const int kb   = (l >> 4) * 8;

    f32x4 acc[6];
#pragma unroll
    for (int n = 0; n < 6; ++n) acc[n] = (f32x4){0.f, 0.f, 0.f, 0.f};

    const float* aptr = ids + arow * Csz + kb;
    const unsigned short* bptr = wB + (jt0 * 64 + l) * 8;   // + ks*6144 per step

    float4 a0 = *(const float4*)(aptr);
    float4 a1 = *(const float4*)(aptr + 4);

    for (int ks = 0; ks < 32; ++ks) {
        float4 n0, n1;
        if (ks < 31) {
            n0 = *(const float4*)(aptr + 32);
            n1 = *(const float4*)(aptr + 36);
        }
        union { short8v s; unsigned int u[4]; } af;
        af.u[0] = f2bf(a0.x) | (f2bf(a0.y) << 16);
        af.u[1] = f2bf(a0.z) | (f2bf(a0.w) << 16);
        af.u[2] = f2bf(a1.x) | (f2bf(a1.y) << 16);
        af.u[3] = f2bf(a1.z) | (f2bf(a1.w) << 16);
#pragma unroll
        for (int n = 0; n < 6; ++n) {
            short8v bf_ = *(const short8v*)(bptr + n * 512);
            acc[n] = __builtin_amdgcn_mfma_f32_16x16x32_bf16(af.s, bf_, acc[n], 0, 0, 0);
        }
        a0 = n0; a1 = n1;
        aptr += 32;
        bptr += 6144;
    }

    const int crow0 = blockIdx.x * 32 + wm * 16 + (l >> 4) * 4;
    const int ccol  = l & 15;
#pragma unroll
    for (int n = 0; n < 6; ++n) {
        const int j = (jt0 + n) * 16 + ccol;
        const float bj = bias[j];
#pragma unroll
        for (int r = 0; r < 4; ++r)
            qkv[(crow0 + r) * NQ + j] = acc[n][r] + bj;
    }
}

// ---------------- fused causal attention (no softmax) ----------------
// TM=32 query rows/block, SN=128 key rows/tile. 512 blocks, 256 threads.
// LDS: q[32][64], kv-union (kT [64][132] then v [128][64]), wei [32][128] = 58 KB
__global__ __launch_bounds__(256) void k_attn(const float* __restrict__ qkv,
                                              float* __restrict__ h) {
    __shared__ float q_lds[32 * 64];
    __shared__ float kvb[64 * 132];
    __shared__ float wei[32 * 128];

    const int tid = threadIdx.x;
    const int u = blockIdx.x;
    int b, i;   // heavy/light pairing: CU gets one i>=32 and one i<32 block
    if (u < 256) { b = u >> 5; i = 32 + (u & 31); }
    else         { int uu = u - 256; b = uu >> 5; i = 31 - (uu & 31); }

    const int base = b * Tsz;
    const int ns = (i * 32 + 31) / 128 + 1;     // # of 128-wide s-tiles

    // stage Q tile [32][64]
#pragma unroll
    for (int kk = 0; kk < 2; ++kk) {
        int idx = kk * 256 + tid;
        int row = idx >> 4, c4 = idx & 15;
        *(float4*)&q_lds[row * 64 + c4 * 4] =
            *(const float4*)&qkv[(base + i * 32 + row) * NQ + c4 * 4];
    }

    const int g5 = tid >> 5;       // 0..7
    const int l5 = tid & 31;       // 0..31
    const int wr0 = g5 * 4;        // wei/out rows: 4 per thread
    const int ws0 = l5 * 4;        // wei cols: 4 per thread
    const int d0 = l5 * 2;         // out dims: 2 per thread

    float acc[4][2];
#pragma unroll
    for (int m = 0; m < 4; ++m) { acc[m][0] = 0.f; acc[m][1] = 0.f; }

    for (int st = 0; st < ns; ++st) {
        __syncthreads();
        // stage K transposed: kT[d][s] stride 132
#pragma unroll
        for (int kk = 0; kk < 8; ++kk) {
            int idx = kk * 256 + tid;
            int srow = idx >> 4, c4 = idx & 15;
            float4 kx = *(const float4*)&qkv[(base + st * 128 + srow) * NQ + 64 + c4 * 4];
            kvb[(c4 * 4 + 0) * 132 + srow] = kx.x;
            kvb[(c4 * 4 + 1) * 132 + srow] = kx.y;
            kvb[(c4 * 4 + 2) * 132 + srow] = kx.z;
            kvb[(c4 * 4 + 3) * 132 + srow] = kx.w;
        }
        __syncthreads();
        // QK^T -> wei tile
        float dot[4][4];
#pragma unroll
        for (int m = 0; m < 4; ++m)
#pragma unroll
            for (int sj = 0; sj < 4; ++sj) dot[m][sj] = 0.f;
#pragma unroll 4
        for (int d4 = 0; d4 < 16; ++d4) {
            float qv[4][4];
#pragma unroll
            for (int m = 0; m < 4; ++m)
                *(float4*)&qv[m][0] = *(const float4*)&q_lds[(wr0 + m) * 64 + d4 * 4];
#pragma unroll
            for (int dd = 0; dd < 4; ++dd) {
                float4 k4 = *(const float4*)&kvb[(d4 * 4 + dd) * 132 + ws0];
#pragma unroll
                for (int m = 0; m < 4; ++m) {
                    dot[m][0] = fmaf(qv[m][dd], k4.x, dot[m][0]);
                    dot[m][1] = fmaf(qv[m][dd], k4.y, dot[m][1]);
                    dot[m][2] = fmaf(qv[m][dd], k4.z, dot[m][2]);
                    dot[m][3] = fmaf(qv[m][dd], k4.w, dot[m][3]);
                }
            }
        }
        const bool last = (st == ns - 1);
#pragma unroll
        for (int m = 0; m < 4; ++m) {
            const int tg = i * 32 + wr0 + m;
            float4 w4;
            float* wp = (float*)&w4;
#pragma unroll
            for (int sj = 0; sj < 4; ++sj) {
                int sg = st * 128 + ws0 + sj;
                wp[sj] = (last && sg > tg) ? 0.f : dot[m][sj];
            }
            *(float4*)&wei[(wr0 + m) * 128 + ws0] = w4;
        }
        __syncthreads();
        // stage V row-major [s][d] into same buffer
#pragma unroll
        for (int kk = 0; kk < 8; ++kk) {
            int idx = kk * 256 + tid;
            int srow = idx >> 4, c4 = idx & 15;
            *(float4*)&kvb[srow * 64 + c4 * 4] =
                *(const float4*)&qkv[(base + st * 128 + srow) * NQ + 128 + c4 * 4];
        }
        __syncthreads();
        // PV: acc += wei @ V
#pragma unroll 8
        for (int s4 = 0; s4 < 32; ++s4) {
            float wv[4][4];
#pragma unroll
            for (int m = 0; m < 4; ++m)
                *(float4*)&wv[m][0] = *(const float4*)&wei[(wr0 + m) * 128 + s4 * 4];
#pragma unroll
            for (int ss = 0; ss < 4; ++ss) {
                float2 v2 = *(const float2*)&kvb[(s4 * 4 + ss) * 64 + d0];
#pragma unroll
                for (int m = 0; m < 4; ++m) {
                    acc[m][0] = fmaf(wv[m][ss], v2.x, acc[m][0]);
                    acc[m][1] = fmaf(wv[m][ss], v2.y, acc[m][1]);
                }
            }
        }
    }
#pragma unroll
    for (int m = 0; m < 4; ++m) {
        float2 o; o.x = acc[m][0]; o.y = acc[m][1];
        *(float2*)&h[(base + i * 32 + wr0 + m) * HSsz + d0] = o;
    }
}

// ---------------- out = h @ W2^T + proj_b : [16384 x 64] x [64 x 1024] ----------------
__global__ __launch_bounds__(256) void k_proj(const float* __restrict__ h,
                                              const float* __restrict__ w2t,
                                              const float* __restrict__ pb,
                                              float* __restrict__ out) {
    __shared__ float hT[64 * 20];   // [d][row], pad 20 keeps b128 alignment
    const int tid = threadIdx.x;
    const int bt0 = blockIdx.x * 16;
#pragma unroll
    for (int kk = 0; kk < 4; ++kk) {
        int idx = kk * 256 + tid;
        int d = idx & 63, row = idx >> 6;            // coalesced global read
        hT[d * 20 + row] = h[(bt0 + row) * HSsz + d];
    }
    __syncthreads();
    const int c0 = tid * 4;
    const float4 pb4 = *(const float4*)&pb[c0];
    float a[16][4];
#pragma unroll
    for (int r = 0; r < 16; ++r) {
        a[r][0] = pb4.x; a[r][1] = pb4.y; a[r][2] = pb4.z; a[r][3] = pb4.w;
    }
#pragma unroll 4
    for (int d = 0; d < 64; ++d) {
        float4 w4 = *(const float4*)&w2t[d * Csz + c0];   // coalesced, L2-hot
        float hv[16];
        *(float4*)&hv[0]  = *(const float4*)&hT[d * 20 + 0];
        *(float4*)&hv[4]  = *(const float4*)&hT[d * 20 + 4];
        *(float4*)&hv[8]  = *(const float4*)&hT[d * 20 + 8];
        *(float4*)&hv[12] = *(const float4*)&hT[d * 20 + 12];
#pragma unroll
        for (int r = 0; r < 16; ++r) {
            a[r][0] = fmaf(hv[r], w4.x, a[r][0]);
            a[r][1] = fmaf(hv[r], w4.y, a[r][1]);
            a[r][2] = fmaf(hv[r], w4.z, a[r][2]);
            a[r][3] = fmaf(hv[r], w4.w, a[r][3]);
        }
    }
#pragma unroll
    for (int r = 0; r < 16; ++r) {
        float4 o; o.x = a[r][0]; o.y = a[r][1]; o.z = a[r][2]; o.w = a[r][3];
        *(float4*)&out[(bt0 + r) * Csz + c0] = o;
    }
}

extern "C" void kernel_launch(void* const* d_in, const int* in_sizes, int n_in,
                              void* d_out, int out_size, void* d_ws, size_t ws_size,
                              hipStream_t stream) {
    const float* ids    = (const float*)d_in[0];
    const float* qkv_w  = (const float*)d_in[1];
    const float* qkv_b  = (const float*)d_in[2];
    const float* proj_w = (const float*)d_in[3];
    const float* proj_b = (const float*)d_in[4];
    float* out = (float*)d_out;

    float* ws  = (float*)d_ws;
    float* qkv = ws;                                   // 16384*192 f32
    float* h   = qkv + 16384 * NQ;                     // 16384*64 f32
    unsigned short* wB = (unsigned short*)(h + 16384 * HSsz);  // 393216 bf16 = 786432 B
    float* w2t = (float*)((char*)wB + 786432);         // 64*1024 f32 (same footprint as before)

    hipLaunchKernelGGL(k_packB,    dim3(96),   dim3(256), 0, stream, qkv_w, wB);
    hipLaunchKernelGGL(k_w2t,      dim3(256),  dim3(256), 0, stream, proj_w, w2t);
    hipLaunchKernelGGL(k_qkv_mfma, dim3(512),  dim3(256), 0, stream, ids, wB, qkv_b, qkv);
    hipLaunchKernelGGL(k_attn,     dim3(512),  dim3(256), 0, stream, qkv, h);
    hipLaunchKernelGGL(k_proj,     dim3(1024), dim3(256), 0, stream, h, w2t, proj_b, out);
}

// Round 3
// 109.077 us; speedup vs baseline: 3.5088x; 1.8576x over previous
//
#include <hip/hip_runtime.h>
#include <hip/hip_bf16.h>

#define Bsz 8
#define Tsz 2048
#define Csz 1024
#define HSsz 64
#define NQ 192   // 3*hs

typedef __attribute__((ext_vector_type(8))) short short8v;
typedef __attribute__((ext_vector_type(4))) float f32x4;

// fp32 -> bf16 round-to-nearest-even (bit pattern)
__device__ __forceinline__ unsigned int f2bf(float f) {
    union { float f; unsigned int u; } v; v.f = f;
    return (v.u + 0x7fffu + ((v.u >> 16) & 1u)) >> 16;
}

// ------------- reduce proj_w over heads: w2t[d][c] = sum_h proj_w[c][h*64+d] -------------
__global__ __launch_bounds__(256) void k_w2t(const float* __restrict__ pw,
                                             float* __restrict__ w2t) {
    int idx = blockIdx.x * 256 + threadIdx.x;
    int d = idx & 63;
    int c = idx >> 6;
    float s = 0.f;
#pragma unroll
    for (int hh = 0; hh < 16; ++hh) s += pw[c * Csz + hh * HSsz + d];
    w2t[d * Csz + c] = s;
}

// ------------- pack qkv_w into per-lane MFMA B fragments, bf16 -------------
__global__ __launch_bounds__(256) void k_packB(const float* __restrict__ w,
                                               unsigned short* __restrict__ wB) {
    int idx = blockIdx.x * 256 + threadIdx.x;   // 24576 threads = 12*32*64
    int l = idx & 63;
    int ksjt = idx >> 6;
    int jt = ksjt % 12, ks = ksjt / 12;
    int j = jt * 16 + (l & 15);
    int k = ks * 32 + (l >> 4) * 8;
    const float* src = &w[j * Csz + k];
    float4 a = *(const float4*)src;
    float4 b = *(const float4*)(src + 4);
    uint4 o;
    o.x = f2bf(a.x) | (f2bf(a.y) << 16);
    o.y = f2bf(a.z) | (f2bf(a.w) << 16);
    o.z = f2bf(b.x) | (f2bf(b.y) << 16);
    o.w = f2bf(b.z) | (f2bf(b.w) << 16);
    *(uint4*)&wB[idx * 8] = o;
}

// ---------------- qkv GEMM via bf16 MFMA -> Qb, Kb (row-major bf16), Vt (transposed bf16) ----
__global__ __launch_bounds__(256) void k_qkv_mfma(const float* __restrict__ ids,
                                                  const unsigned short* __restrict__ wB,
                                                  const float* __restrict__ bias,
                                                  unsigned short* __restrict__ Qb,
                                                  unsigned short* __restrict__ Kb,
                                                  unsigned short* __restrict__ Vt) {
    const int tid = threadIdx.x;
    const int wv = tid >> 6;
    const int l  = tid & 63;
    const int wm = wv & 1, wn = wv >> 1;
    const int jt0 = wn * 6;

    const int arow = blockIdx.x * 32 + wm * 16 + (l & 15);
    const int kb   = (l >> 4) * 8;

    f32x4 acc[6];
#pragma unroll
    for (int n = 0; n < 6; ++n) acc[n] = (f32x4){0.f, 0.f, 0.f, 0.f};

    const float* aptr = ids + arow * Csz + kb;
    const unsigned short* bptr = wB + (jt0 * 64 + l) * 8;

    float4 a0 = *(const float4*)(aptr);
    float4 a1 = *(const float4*)(aptr + 4);

    for (int ks = 0; ks < 32; ++ks) {
        float4 n0, n1;
        if (ks < 31) {
            n0 = *(const float4*)(aptr + 32);
            n1 = *(const float4*)(aptr + 36);
        }
        union { short8v s; unsigned int u[4]; } af;
        af.u[0] = f2bf(a0.x) | (f2bf(a0.y) << 16);
        af.u[1] = f2bf(a0.z) | (f2bf(a0.w) << 16);
        af.u[2] = f2bf(a1.x) | (f2bf(a1.y) << 16);
        af.u[3] = f2bf(a1.z) | (f2bf(a1.w) << 16);
#pragma unroll
        for (int n = 0; n < 6; ++n) {
            short8v bf_ = *(const short8v*)(bptr + n * 512);
            acc[n] = __builtin_amdgcn_mfma_f32_16x16x32_bf16(af.s, bf_, acc[n], 0, 0, 0);
        }
        a0 = n0; a1 = n1;
        aptr += 32;
        bptr += 6144;
    }

    const int crow0 = blockIdx.x * 32 + wm * 16 + (l >> 4) * 4;
    const int ccol  = l & 15;
#pragma unroll
    for (int n = 0; n < 6; ++n) {
        const int jb = jt0 + n;                 // 16-col block index 0..11
        const int j  = jb * 16 + ccol;
        const float bj = bias[j];
        float v0 = acc[n][0] + bj, v1 = acc[n][1] + bj;
        float v2 = acc[n][2] + bj, v3 = acc[n][3] + bj;
        if (jb < 4) {                           // Q rows
            unsigned short* q = &Qb[crow0 * HSsz + j];
            q[0] = (unsigned short)f2bf(v0); q[HSsz] = (unsigned short)f2bf(v1);
            q[2 * HSsz] = (unsigned short)f2bf(v2); q[3 * HSsz] = (unsigned short)f2bf(v3);
        } else if (jb < 8) {                    // K rows
            unsigned short* k = &Kb[crow0 * HSsz + (j - 64)];
            k[0] = (unsigned short)f2bf(v0); k[HSsz] = (unsigned short)f2bf(v1);
            k[2 * HSsz] = (unsigned short)f2bf(v2); k[3 * HSsz] = (unsigned short)f2bf(v3);
        } else {                                // V -> transposed Vt[b][d][t]
            int d = j - 128;
            uint2 pk;
            pk.x = f2bf(v0) | (f2bf(v1) << 16);
            pk.y = f2bf(v2) | (f2bf(v3) << 16);
            *(uint2*)&Vt[((crow0 >> 11) * HSsz + d) * Tsz + (crow0 & 2047)] = pk;
        }
    }
}

// ---------------- fused causal attention via bf16 MFMA (no softmax) ----------------
// strip = 16 q-rows. Heavy block: 1 strip (si>=64), 4 waves split its s-tiles 4-way.
// Pair block: strips (63-rr, rr), each split 2-way. Every wave <= 8 s-tiles of 64.
// Swapped QK^T (S^T = K*Q^T) keeps t lane-local; S bounced through per-wave LDS.
__global__ __launch_bounds__(256) void k_attn_mfma(const unsigned short* __restrict__ Qb,
                                                   const unsigned short* __restrict__ Kb,
                                                   const unsigned short* __restrict__ Vt,
                                                   float* __restrict__ h) {
    __shared__ __align__(16) unsigned int s_su[4][576];   // per-wave S tile [16][72] bf16
    __shared__ float s_o[4][1024];                         // per-wave partial O [16][64]

    const int tid = threadIdx.x;
    const int w  = tid >> 6;
    const int l  = tid & 63;
    const int lg = l >> 4;      // 0..3
    const int ll = l & 15;      // 0..15

    const int u = blockIdx.x;
    const int b = u / 96;
    const int r = u - b * 96;

    int si, sub, nsub;
    const bool heavy = (r < 64);
    if (heavy) { si = 64 + r; sub = w; nsub = 4; }
    else {
        int rr = r - 64;
        si = (w < 2) ? (63 - rr) : rr;
        sub = w & 1; nsub = 2;
    }
    const int nT  = (si >> 2) + 1;               // s-tiles of 64 for this strip
    const int qn  = nT / nsub, rem = nT % nsub;
    const int t0  = sub * qn + (sub < rem ? sub : rem);
    const int cnt = qn + (sub < rem ? 1 : 0);

    const int q0 = si * 16;                       // within batch
    const int bbase = b * Tsz;

    // Q fragments (2 k-steps over d=0..63), held in registers
    short8v qf0, qf1;
    {
        const unsigned short* qp = Qb + (size_t)(bbase + q0 + ll) * HSsz + lg * 8;
        qf0 = *(const short8v*)qp;
        qf1 = *(const short8v*)(qp + 32);
    }

    f32x4 oacc[4];
#pragma unroll
    for (int n = 0; n < 4; ++n) oacc[n] = (f32x4){0.f, 0.f, 0.f, 0.f};

    for (int tile = t0; tile < t0 + cnt; ++tile) {
        const int s0 = tile * 64;
        // ---- S^T = K * Q^T  (M=s, N=t, K=d) ----
        const unsigned short* kp = Kb + (size_t)(bbase + s0 + ll) * HSsz + lg * 8;
        f32x4 sacc[4];
#pragma unroll
        for (int m = 0; m < 4; ++m) sacc[m] = (f32x4){0.f, 0.f, 0.f, 0.f};
#pragma unroll
        for (int m = 0; m < 4; ++m) {
            short8v k0 = *(const short8v*)(kp + m * 16 * HSsz);
            short8v k1 = *(const short8v*)(kp + m * 16 * HSsz + 32);
            sacc[m] = __builtin_amdgcn_mfma_f32_16x16x32_bf16(k0, qf0, sacc[m], 0, 0, 0);
            sacc[m] = __builtin_amdgcn_mfma_f32_16x16x32_bf16(k1, qf1, sacc[m], 0, 0, 0);
        }
        // causal mask on the diagonal tile only
        if (tile == nT - 1) {
            const int tg = q0 + ll;
#pragma unroll
            for (int m = 0; m < 4; ++m)
#pragma unroll
                for (int rr2 = 0; rr2 < 4; ++rr2) {
                    int sg = s0 + 16 * m + 4 * lg + rr2;
                    if (sg > tg) sacc[m][rr2] = 0.f;
                }
        }
        // ---- pack S to bf16 in per-wave LDS: [t=ll][s], row stride 72 bf16 ----
#pragma unroll
        for (int m = 0; m < 4; ++m) {
            union { __hip_bfloat162 h2; unsigned int u; } p0, p1;
            p0.h2 = __float22bfloat162_rn(float2{sacc[m][0], sacc[m][1]});
            p1.h2 = __float22bfloat162_rn(float2{sacc[m][2], sacc[m][3]});
            uint2 pk; pk.x = p0.u; pk.y = p1.u;
            *(uint2*)&s_su[w][ll * 36 + 8 * m + 2 * lg] = pk;   // bf16 idx: ll*72 + 16m + 4lg
        }
        // ---- read A fragments (per-wave private; compiler inserts lgkmcnt) ----
        union { uint4 u4; short8v s; } a0, a1;
        a0.u4 = *(const uint4*)&s_su[w][ll * 36 + 4 * lg];        // s = 8*lg + b
        a1.u4 = *(const uint4*)&s_su[w][ll * 36 + 16 + 4 * lg];   // s = 32 + 8*lg + b
        // ---- O += S * V  (M=t, N=d, K=s), B-frag from transposed Vt ----
        const unsigned short* vp = Vt + (size_t)(b * HSsz + ll) * Tsz + s0 + lg * 8;
#pragma unroll
        for (int n = 0; n < 4; ++n) {
            short8v v0 = *(const short8v*)(vp + n * 16 * Tsz);
            short8v v1 = *(const short8v*)(vp + n * 16 * Tsz + 32);
            oacc[n] = __builtin_amdgcn_mfma_f32_16x16x32_bf16(a0.s, v0, oacc[n], 0, 0, 0);
            oacc[n] = __builtin_amdgcn_mfma_f32_16x16x32_bf16(a1.s, v1, oacc[n], 0, 0, 0);
        }
    }

    // ---- write partial O to LDS, combine across waves, store h (fp32) ----
#pragma unroll
    for (int n = 0; n < 4; ++n)
#pragma unroll
        for (int rr2 = 0; rr2 < 4; ++rr2)
            s_o[w][(4 * lg + rr2) * 64 + 16 * n + ll] = oacc[n][rr2];
    __syncthreads();

    if (heavy) {
        const int e = tid * 4;
        float4 v = *(const float4*)&s_o[0][e];
        const float4 v1 = *(const float4*)&s_o[1][e];
        const float4 v2 = *(const float4*)&s_o[2][e];
        const float4 v3 = *(const float4*)&s_o[3][e];
        v.x += v1.x + v2.x + v3.x; v.y += v1.y + v2.y + v3.y;
        v.z += v1.z + v2.z + v3.z; v.w += v1.w + v2.w + v3.w;
        const int t = e >> 6, d = e & 63;
        *(float4*)&h[(size_t)(bbase + q0 + t) * HSsz + d] = v;
    } else {
        const int half = tid >> 7;              // 0: strip 63-rr, 1: strip rr
        const int tt2 = tid & 127;
        const int e = tt2 * 8;
        const int rr = r - 64;
        const int sih = half ? rr : (63 - rr);
        float4 x0 = *(const float4*)&s_o[2 * half][e];
        float4 y0 = *(const float4*)&s_o[2 * half + 1][e];
        float4 x1 = *(const float4*)&s_o[2 * half][e + 4];
        float4 y1 = *(const float4*)&s_o[2 * half + 1][e + 4];
        x0.x += y0.x; x0.y += y0.y; x0.z += y0.z; x0.w += y0.w;
        x1.x += y1.x; x1.y += y1.y; x1.z += y1.z; x1.w += y1.w;
        const int t = e >> 6, d = e & 63;
        float* hp = &h[(size_t)(bbase + sih * 16 + t) * HSsz + d];
        *(float4*)hp = x0;
        *(float4*)(hp + 4) = x1;
    }
}

// ---------------- out = h @ W2^T + proj_b : [16384 x 64] x [64 x 1024] ----------------
__global__ __launch_bounds__(256) void k_proj(const float* __restrict__ h,
                                              const float* __restrict__ w2t,
                                              const float* __restrict__ pb,
                                              float* __restrict__ out) {
    __shared__ float hT[64 * 20];
    const int tid = threadIdx.x;
    const int bt0 = blockIdx.x * 16;
#pragma unroll
    for (int kk = 0; kk < 4; ++kk) {
        int idx = kk * 256 + tid;
        int d = idx & 63, row = idx >> 6;
        hT[d * 20 + row] = h[(bt0 + row) * HSsz + d];
    }
    __syncthreads();
    const int c0 = tid * 4;
    const float4 pb4 = *(const float4*)&pb[c0];
    float a[16][4];
#pragma unroll
    for (int r = 0; r < 16; ++r) {
        a[r][0] = pb4.x; a[r][1] = pb4.y; a[r][2] = pb4.z; a[r][3] = pb4.w;
    }
#pragma unroll 4
    for (int d = 0; d < 64; ++d) {
        float4 w4 = *(const float4*)&w2t[d * Csz + c0];
        float hv[16];
        *(float4*)&hv[0]  = *(const float4*)&hT[d * 20 + 0];
        *(float4*)&hv[4]  = *(const float4*)&hT[d * 20 + 4];
        *(float4*)&hv[8]  = *(const float4*)&hT[d * 20 + 8];
        *(float4*)&hv[12] = *(const float4*)&hT[d * 20 + 12];
#pragma unroll
        for (int r = 0; r < 16; ++r) {
            a[r][0] = fmaf(hv[r], w4.x, a[r][0]);
            a[r][1] = fmaf(hv[r], w4.y, a[r][1]);
            a[r][2] = fmaf(hv[r], w4.z, a[r][2]);
            a[r][3] = fmaf(hv[r], w4.w, a[r][3]);
        }
    }
#pragma unroll
    for (int r = 0; r < 16; ++r) {
        float4 o; o.x = a[r][0]; o.y = a[r][1]; o.z = a[r][2]; o.w = a[r][3];
        *(float4*)&out[(bt0 + r) * Csz + c0] = o;
    }
}

extern "C" void kernel_launch(void* const* d_in, const int* in_sizes, int n_in,
                              void* d_out, int out_size, void* d_ws, size_t ws_size,
                              hipStream_t stream) {
    const float* ids    = (const float*)d_in[0];
    const float* qkv_w  = (const float*)d_in[1];
    const float* qkv_b  = (const float*)d_in[2];
    const float* proj_w = (const float*)d_in[3];
    const float* proj_b = (const float*)d_in[4];
    float* out = (float*)d_out;

    unsigned short* Qb = (unsigned short*)d_ws;        // 16384*64 bf16 = 2 MB
    unsigned short* Kb = Qb + 16384 * HSsz;            // 2 MB
    unsigned short* Vt = Kb + 16384 * HSsz;            // 2 MB (transposed [b][d][t])
    float* h   = (float*)(Vt + 16384 * HSsz);          // 4 MB
    unsigned short* wB = (unsigned short*)(h + 16384 * HSsz);  // 768 KB
    float* w2t = (float*)(wB + 393216);                // 256 KB

    hipLaunchKernelGGL(k_packB,     dim3(96),   dim3(256), 0, stream, qkv_w, wB);
    hipLaunchKernelGGL(k_w2t,       dim3(256),  dim3(256), 0, stream, proj_w, w2t);
    hipLaunchKernelGGL(k_qkv_mfma,  dim3(512),  dim3(256), 0, stream, ids, wB, qkv_b, Qb, Kb, Vt);
    hipLaunchKernelGGL(k_attn_mfma, dim3(768),  dim3(256), 0, stream, Qb, Kb, Vt, h);
    hipLaunchKernelGGL(k_proj,      dim3(1024), dim3(256), 0, stream, h, w2t, proj_b, out);
}

// Round 4
// 93.124 us; speedup vs baseline: 4.1099x; 1.1713x over previous
//
#include <hip/hip_runtime.h>
#include <hip/hip_bf16.h>

#define Bsz 8
#define Tsz 2048
#define Csz 1024
#define HSsz 64
#define NQ 192   // 3*hs

typedef __attribute__((ext_vector_type(8))) short short8v;
typedef __attribute__((ext_vector_type(4))) float f32x4;

// fp32 -> bf16 round-to-nearest-even (bit pattern)
__device__ __forceinline__ unsigned int f2bf(float f) {
    union { float f; unsigned int u; } v; v.f = f;
    return (v.u + 0x7fffu + ((v.u >> 16) & 1u)) >> 16;
}

// ------------- prep: pack qkv_w B-frags (blocks 0..95) + W2 A-frags (blocks 96..127) -------------
__global__ __launch_bounds__(256) void k_prep(const float* __restrict__ qw,
                                              const float* __restrict__ pw,
                                              unsigned short* __restrict__ wB,
                                              unsigned short* __restrict__ w2a) {
    const int blk = blockIdx.x;
    if (blk < 96) {
        int idx = blk * 256 + threadIdx.x;      // 24576 threads = 32ks*12jt*64l
        int l = idx & 63;
        int ksjt = idx >> 6;
        int jt = ksjt % 12, ks = ksjt / 12;
        int j = jt * 16 + (l & 15);
        int k = ks * 32 + (l >> 4) * 8;
        const float* src = &qw[j * Csz + k];
        float4 a = *(const float4*)src;
        float4 b = *(const float4*)(src + 4);
        uint4 o;
        o.x = f2bf(a.x) | (f2bf(a.y) << 16);
        o.y = f2bf(a.z) | (f2bf(a.w) << 16);
        o.z = f2bf(b.x) | (f2bf(b.y) << 16);
        o.w = f2bf(b.z) | (f2bf(b.w) << 16);
        *(uint4*)&wB[(size_t)idx * 8] = o;
    } else {
        // w2a[(ks*64 + m)*64 + l][8] ; value b = sum_h pw[(m*16+(l&15))*C + h*64 + ks*32+(l>>4)*8 + b]
        int idx = (blk - 96) * 256 + threadIdx.x;   // 0..8191 = 2ks*64m*64l
        int l = idx & 63;
        int rest = idx >> 6;
        int m = rest & 63, ks = rest >> 6;
        int c = m * 16 + (l & 15);
        int d0 = ks * 32 + (l >> 4) * 8;
        float s0 = 0, s1 = 0, s2 = 0, s3 = 0, s4 = 0, s5 = 0, s6 = 0, s7 = 0;
#pragma unroll
        for (int hh = 0; hh < 16; ++hh) {
            const float* p = &pw[c * Csz + hh * HSsz + d0];
            float4 x = *(const float4*)p;
            float4 y = *(const float4*)(p + 4);
            s0 += x.x; s1 += x.y; s2 += x.z; s3 += x.w;
            s4 += y.x; s5 += y.y; s6 += y.z; s7 += y.w;
        }
        uint4 o;
        o.x = f2bf(s0) | (f2bf(s1) << 16);
        o.y = f2bf(s2) | (f2bf(s3) << 16);
        o.z = f2bf(s4) | (f2bf(s5) << 16);
        o.w = f2bf(s6) | (f2bf(s7) << 16);
        *(uint4*)&w2a[(size_t)idx * 8] = o;
    }
}

// ---------------- qkv GEMM via bf16 MFMA, K split across 2 wave-groups ----------------
// 512 thr = 8 waves: wm=row half, wn=col half, wk=K half. 512 blocks (32 rows each).
__global__ __launch_bounds__(512, 4) void k_qkv_mfma(const float* __restrict__ ids,
                                                     const unsigned short* __restrict__ wB,
                                                     const float* __restrict__ bias,
                                                     unsigned short* __restrict__ Qb,
                                                     unsigned short* __restrict__ Kb,
                                                     unsigned short* __restrict__ Vt) {
    __shared__ f32x4 s_comb[4][64][6];   // 24 KB: wk=1 partial accs

    const int tid = threadIdx.x;
    const int wv = tid >> 6;
    const int l  = tid & 63;
    const int wm = wv & 1;
    const int wn = (wv >> 1) & 1;
    const int wk = wv >> 2;
    const int jt0 = wn * 6;

    const int arow = blockIdx.x * 32 + wm * 16 + (l & 15);
    const int kb   = (l >> 4) * 8;

    f32x4 acc[6];
#pragma unroll
    for (int n = 0; n < 6; ++n) acc[n] = (f32x4){0.f, 0.f, 0.f, 0.f};

    const float* aptr = ids + (size_t)arow * Csz + wk * 512 + kb;
    const unsigned short* bptr = wB + (size_t)wk * 16 * 6144 + (jt0 * 64 + l) * 8;

    float4 a0 = *(const float4*)(aptr);
    float4 a1 = *(const float4*)(aptr + 4);
    short8v bcur[6];
#pragma unroll
    for (int n = 0; n < 6; ++n) bcur[n] = *(const short8v*)(bptr + n * 512);

    for (int ks = 0; ks < 16; ++ks) {
        // pack current A first, then overwrite a0/a1 with prefetch
        union { short8v s; unsigned int u[4]; } af;
        af.u[0] = f2bf(a0.x) | (f2bf(a0.y) << 16);
        af.u[1] = f2bf(a0.z) | (f2bf(a0.w) << 16);
        af.u[2] = f2bf(a1.x) | (f2bf(a1.y) << 16);
        af.u[3] = f2bf(a1.z) | (f2bf(a1.w) << 16);
        short8v bnext[6];
        if (ks < 15) {
            a0 = *(const float4*)(aptr + 32);
            a1 = *(const float4*)(aptr + 36);
#pragma unroll
            for (int n = 0; n < 6; ++n) bnext[n] = *(const short8v*)(bptr + 6144 + n * 512);
        }
#pragma unroll
        for (int n = 0; n < 6; ++n)
            acc[n] = __builtin_amdgcn_mfma_f32_16x16x32_bf16(af.s, bcur[n], acc[n], 0, 0, 0);
#pragma unroll
        for (int n = 0; n < 6; ++n) bcur[n] = bnext[n];
        aptr += 32;
        bptr += 6144;
    }

    const int wid2 = wm * 2 + wn;
    if (wk == 1) {
#pragma unroll
        for (int n = 0; n < 6; ++n) s_comb[wid2][l][n] = acc[n];
    }
    __syncthreads();
    if (wk == 1) return;

    const int crow0 = blockIdx.x * 32 + wm * 16 + (l >> 4) * 4;
    const int ccol  = l & 15;
#pragma unroll
    for (int n = 0; n < 6; ++n) {
        f32x4 other = s_comb[wid2][l][n];
        const int jb = jt0 + n;
        const int j  = jb * 16 + ccol;
        const float bj = bias[j];
        float v0 = acc[n][0] + other[0] + bj, v1 = acc[n][1] + other[1] + bj;
        float v2 = acc[n][2] + other[2] + bj, v3 = acc[n][3] + other[3] + bj;
        if (jb < 4) {                           // Q
            unsigned short* q = &Qb[(size_t)crow0 * HSsz + j];
            q[0] = (unsigned short)f2bf(v0); q[HSsz] = (unsigned short)f2bf(v1);
            q[2 * HSsz] = (unsigned short)f2bf(v2); q[3 * HSsz] = (unsigned short)f2bf(v3);
        } else if (jb < 8) {                    // K
            unsigned short* k = &Kb[(size_t)crow0 * HSsz + (j - 64)];
            k[0] = (unsigned short)f2bf(v0); k[HSsz] = (unsigned short)f2bf(v1);
            k[2 * HSsz] = (unsigned short)f2bf(v2); k[3 * HSsz] = (unsigned short)f2bf(v3);
        } else {                                // V -> Vt[b][d][t]
            int d = j - 128;
            uint2 pk;
            pk.x = f2bf(v0) | (f2bf(v1) << 16);
            pk.y = f2bf(v2) | (f2bf(v3) << 16);
            *(uint2*)&Vt[((size_t)(crow0 >> 11) * HSsz + d) * Tsz + (crow0 & 2047)] = pk;
        }
    }
}

// ---------------- fused causal attention via bf16 MFMA (no softmax) ----------------
__global__ __launch_bounds__(256) void k_attn_mfma(const unsigned short* __restrict__ Qb,
                                                   const unsigned short* __restrict__ Kb,
                                                   const unsigned short* __restrict__ Vt,
                                                   unsigned short* __restrict__ hb) {
    __shared__ __align__(16) unsigned int s_su[4][576];   // per-wave S tile [16][72] bf16
    __shared__ float s_o[4][1024];                         // per-wave partial O [16][64]

    const int tid = threadIdx.x;
    const int w  = tid >> 6;
    const int l  = tid & 63;
    const int lg = l >> 4;
    const int ll = l & 15;

    const int u = blockIdx.x;
    const int b = u / 96;
    const int r = u - b * 96;

    int si, sub, nsub;
    const bool heavy = (r < 64);
    if (heavy) { si = 64 + r; sub = w; nsub = 4; }
    else {
        int rr = r - 64;
        si = (w < 2) ? (63 - rr) : rr;
        sub = w & 1; nsub = 2;
    }
    const int nT  = (si >> 2) + 1;
    const int qn  = nT / nsub, rem = nT % nsub;
    const int t0  = sub * qn + (sub < rem ? sub : rem);
    const int cnt = qn + (sub < rem ? 1 : 0);

    const int q0 = si * 16;
    const int bbase = b * Tsz;

    short8v qf0, qf1;
    {
        const unsigned short* qp = Qb + (size_t)(bbase + q0 + ll) * HSsz + lg * 8;
        qf0 = *(const short8v*)qp;
        qf1 = *(const short8v*)(qp + 32);
    }

    f32x4 oacc[4];
#pragma unroll
    for (int n = 0; n < 4; ++n) oacc[n] = (f32x4){0.f, 0.f, 0.f, 0.f};

    for (int tile = t0; tile < t0 + cnt; ++tile) {
        const int s0 = tile * 64;
        const unsigned short* kp = Kb + (size_t)(bbase + s0 + ll) * HSsz + lg * 8;
        f32x4 sacc[4];
#pragma unroll
        for (int m = 0; m < 4; ++m) sacc[m] = (f32x4){0.f, 0.f, 0.f, 0.f};
#pragma unroll
        for (int m = 0; m < 4; ++m) {
            short8v k0 = *(const short8v*)(kp + m * 16 * HSsz);
            short8v k1 = *(const short8v*)(kp + m * 16 * HSsz + 32);
            sacc[m] = __builtin_amdgcn_mfma_f32_16x16x32_bf16(k0, qf0, sacc[m], 0, 0, 0);
            sacc[m] = __builtin_amdgcn_mfma_f32_16x16x32_bf16(k1, qf1, sacc[m], 0, 0, 0);
        }
        if (tile == nT - 1) {
            const int tg = q0 + ll;
#pragma unroll
            for (int m = 0; m < 4; ++m)
#pragma unroll
                for (int rr2 = 0; rr2 < 4; ++rr2) {
                    int sg = s0 + 16 * m + 4 * lg + rr2;
                    if (sg > tg) sacc[m][rr2] = 0.f;
                }
        }
#pragma unroll
        for (int m = 0; m < 4; ++m) {
            uint2 pk;
            pk.x = f2bf(sacc[m][0]) | (f2bf(sacc[m][1]) << 16);
            pk.y = f2bf(sacc[m][2]) | (f2bf(sacc[m][3]) << 16);
            *(uint2*)&s_su[w][ll * 36 + 8 * m + 2 * lg] = pk;
        }
        union { uint4 u4; short8v s; } a0, a1;
        a0.u4 = *(const uint4*)&s_su[w][ll * 36 + 4 * lg];
        a1.u4 = *(const uint4*)&s_su[w][ll * 36 + 16 + 4 * lg];
        const unsigned short* vp = Vt + (size_t)(b * HSsz + ll) * Tsz + s0 + lg * 8;
#pragma unroll
        for (int n = 0; n < 4; ++n) {
            short8v v0 = *(const short8v*)(vp + n * 16 * Tsz);
            short8v v1 = *(const short8v*)(vp + n * 16 * Tsz + 32);
            oacc[n] = __builtin_amdgcn_mfma_f32_16x16x32_bf16(a0.s, v0, oacc[n], 0, 0, 0);
            oacc[n] = __builtin_amdgcn_mfma_f32_16x16x32_bf16(a1.s, v1, oacc[n], 0, 0, 0);
        }
    }

#pragma unroll
    for (int n = 0; n < 4; ++n)
#pragma unroll
        for (int rr2 = 0; rr2 < 4; ++rr2)
            s_o[w][(4 * lg + rr2) * 64 + 16 * n + ll] = oacc[n][rr2];
    __syncthreads();

    if (heavy) {
        const int e = tid * 4;
        float4 v = *(const float4*)&s_o[0][e];
        const float4 v1 = *(const float4*)&s_o[1][e];
        const float4 v2 = *(const float4*)&s_o[2][e];
        const float4 v3 = *(const float4*)&s_o[3][e];
        v.x += v1.x + v2.x + v3.x; v.y += v1.y + v2.y + v3.y;
        v.z += v1.z + v2.z + v3.z; v.w += v1.w + v2.w + v3.w;
        const int t = e >> 6, d = e & 63;
        uint2 pk;
        pk.x = f2bf(v.x) | (f2bf(v.y) << 16);
        pk.y = f2bf(v.z) | (f2bf(v.w) << 16);
        *(uint2*)&hb[(size_t)(bbase + q0 + t) * HSsz + d] = pk;
    } else {
        const int half = tid >> 7;
        const int tt2 = tid & 127;
        const int e = tt2 * 8;
        const int rr = r - 64;
        const int sih = half ? rr : (63 - rr);
        float4 x0 = *(const float4*)&s_o[2 * half][e];
        float4 y0 = *(const float4*)&s_o[2 * half + 1][e];
        float4 x1 = *(const float4*)&s_o[2 * half][e + 4];
        float4 y1 = *(const float4*)&s_o[2 * half + 1][e + 4];
        x0.x += y0.x; x0.y += y0.y; x0.z += y0.z; x0.w += y0.w;
        x1.x += y1.x; x1.y += y1.y; x1.z += y1.z; x1.w += y1.w;
        const int t = e >> 6, d = e & 63;
        uint4 pk;
        pk.x = f2bf(x0.x) | (f2bf(x0.y) << 16);
        pk.y = f2bf(x0.z) | (f2bf(x0.w) << 16);
        pk.z = f2bf(x1.x) | (f2bf(x1.y) << 16);
        pk.w = f2bf(x1.z) | (f2bf(x1.w) << 16);
        *(uint4*)&hb[(size_t)(bbase + sih * 16 + t) * HSsz + d] = pk;
    }
}

// ---------------- out = h @ W2^T + pb via swapped-operand MFMA ----------------
// A = W2 frags (M=c), B = h frags (N=t), K=64 (2 MFMA). D: col=t (lane&15),
// rows = 4 consecutive c -> direct float4 stores. 1024 blocks x 256 thr;
// block = 16 t rows x 1024 c; wave w owns c-frags m = w*16..w*16+15.
__global__ __launch_bounds__(256) void k_proj_mfma(const unsigned short* __restrict__ h,
                                                   const unsigned short* __restrict__ w2a,
                                                   const float* __restrict__ pb,
                                                   float* __restrict__ out) {
    const int tid = threadIdx.x;
    const int w = tid >> 6, l = tid & 63;
    const int t0 = blockIdx.x * 16;

    const unsigned short* hp = h + (size_t)(t0 + (l & 15)) * HSsz + (l >> 4) * 8;
    short8v hb0 = *(const short8v*)hp;          // d = 0..31 slice
    short8v hb1 = *(const short8v*)(hp + 32);   // d = 32..63 slice

    const int row = (l >> 4) * 4;
    const int tcol = l & 15;
    const size_t outrow = (size_t)(t0 + tcol) * Csz;

#pragma unroll 2
    for (int m = w * 16; m < w * 16 + 16; ++m) {
        const unsigned short* ap = w2a + (size_t)(m * 64 + l) * 8;
        short8v a0 = *(const short8v*)ap;
        short8v a1 = *(const short8v*)(ap + 32768);   // ks=1 plane: 64*64*8
        f32x4 acc = (f32x4){0.f, 0.f, 0.f, 0.f};
        acc = __builtin_amdgcn_mfma_f32_16x16x32_bf16(a0, hb0, acc, 0, 0, 0);
        acc = __builtin_amdgcn_mfma_f32_16x16x32_bf16(a1, hb1, acc, 0, 0, 0);
        const int c0 = m * 16 + row;
        const float4 pv = *(const float4*)&pb[c0];
        float4 o;
        o.x = acc[0] + pv.x; o.y = acc[1] + pv.y;
        o.z = acc[2] + pv.z; o.w = acc[3] + pv.w;
        *(float4*)&out[outrow + c0] = o;
    }
}

extern "C" void kernel_launch(void* const* d_in, const int* in_sizes, int n_in,
                              void* d_out, int out_size, void* d_ws, size_t ws_size,
                              hipStream_t stream) {
    const float* ids    = (const float*)d_in[0];
    const float* qkv_w  = (const float*)d_in[1];
    const float* qkv_b  = (const float*)d_in[2];
    const float* proj_w = (const float*)d_in[3];
    const float* proj_b = (const float*)d_in[4];
    float* out = (float*)d_out;

    unsigned short* Qb  = (unsigned short*)d_ws;       // 2 MB
    unsigned short* Kb  = Qb + 16384 * HSsz;           // 2 MB
    unsigned short* Vt  = Kb + 16384 * HSsz;           // 2 MB ([b][d][t])
    unsigned short* hb  = Vt + 16384 * HSsz;           // 2 MB (bf16 h)
    unsigned short* wB  = hb + 16384 * HSsz;           // 384 KB
    unsigned short* w2a = wB + 196608;                 // 128 KB

    hipLaunchKernelGGL(k_prep,      dim3(128),  dim3(256), 0, stream, qkv_w, proj_w, wB, w2a);
    hipLaunchKernelGGL(k_qkv_mfma,  dim3(512),  dim3(512), 0, stream, ids, wB, qkv_b, Qb, Kb, Vt);
    hipLaunchKernelGGL(k_attn_mfma, dim3(768),  dim3(256), 0, stream, Qb, Kb, Vt, hb);
    hipLaunchKernelGGL(k_proj_mfma, dim3(1024), dim3(256), 0, stream, hb, w2a, proj_b, out);
}

// Round 5
// 83.637 us; speedup vs baseline: 4.5761x; 1.1134x over previous
//
#include <hip/hip_runtime.h>
#include <hip/hip_bf16.h>

#define Bsz 8
#define Tsz 2048
#define Csz 1024
#define HSsz 64
#define NQ 192   // 3*hs

typedef __attribute__((ext_vector_type(8))) short short8v;
typedef __attribute__((ext_vector_type(4))) float f32x4;

// fp32 -> bf16 round-to-nearest-even (bit pattern)
__device__ __forceinline__ unsigned int f2bf(float f) {
    union { float f; unsigned int u; } v; v.f = f;
    return (v.u + 0x7fffu + ((v.u >> 16) & 1u)) >> 16;
}

__device__ __forceinline__ unsigned int pk2bf(float lo, float hi) {
    union { __hip_bfloat162 h2; unsigned int u; } cv;
    cv.h2 = __float22bfloat162_rn(float2{lo, hi});
    return cv.u;
}

// ------------- prep: pack qkv_w B-frags (blocks 0..95) + W2 A-frags (blocks 96..127) -------------
__global__ __launch_bounds__(256) void k_prep(const float* __restrict__ qw,
                                              const float* __restrict__ pw,
                                              unsigned short* __restrict__ wB,
                                              unsigned short* __restrict__ w2a) {
    const int blk = blockIdx.x;
    if (blk < 96) {
        int idx = blk * 256 + threadIdx.x;      // 24576 threads = 32ks*12jt*64l
        int l = idx & 63;
        int ksjt = idx >> 6;
        int jt = ksjt % 12, ks = ksjt / 12;
        int j = jt * 16 + (l & 15);
        int k = ks * 32 + (l >> 4) * 8;
        const float* src = &qw[j * Csz + k];
        float4 a = *(const float4*)src;
        float4 b = *(const float4*)(src + 4);
        uint4 o;
        o.x = f2bf(a.x) | (f2bf(a.y) << 16);
        o.y = f2bf(a.z) | (f2bf(a.w) << 16);
        o.z = f2bf(b.x) | (f2bf(b.y) << 16);
        o.w = f2bf(b.z) | (f2bf(b.w) << 16);
        *(uint4*)&wB[(size_t)idx * 8] = o;
    } else {
        int idx = (blk - 96) * 256 + threadIdx.x;   // 0..8191 = 2ks*64m*64l
        int l = idx & 63;
        int rest = idx >> 6;
        int m = rest & 63, ks = rest >> 6;
        int c = m * 16 + (l & 15);
        int d0 = ks * 32 + (l >> 4) * 8;
        float s0 = 0, s1 = 0, s2 = 0, s3 = 0, s4 = 0, s5 = 0, s6 = 0, s7 = 0;
#pragma unroll
        for (int hh = 0; hh < 16; ++hh) {
            const float* p = &pw[c * Csz + hh * HSsz + d0];
            float4 x = *(const float4*)p;
            float4 y = *(const float4*)(p + 4);
            s0 += x.x; s1 += x.y; s2 += x.z; s3 += x.w;
            s4 += y.x; s5 += y.y; s6 += y.z; s7 += y.w;
        }
        uint4 o;
        o.x = f2bf(s0) | (f2bf(s1) << 16);
        o.y = f2bf(s2) | (f2bf(s3) << 16);
        o.z = f2bf(s4) | (f2bf(s5) << 16);
        o.w = f2bf(s6) | (f2bf(s7) << 16);
        *(uint4*)&w2a[(size_t)idx * 8] = o;
    }
}

// ---------------- qkv GEMM via bf16 MFMA, LDS-staged A (coalesced) ----------------
// 512 thr = 8 waves: wm(2 row-slabs) x wn(4 col-groups of 48). Block tile 32x192.
// A staged per 64-float K-chunk into padded [32][68] LDS, double-buffered, 1 barrier/chunk.
__global__ __launch_bounds__(512, 4) void k_qkv_mfma(const float* __restrict__ ids,
                                                     const unsigned short* __restrict__ wB,
                                                     const float* __restrict__ bias,
                                                     unsigned short* __restrict__ Qb,
                                                     unsigned short* __restrict__ Kb,
                                                     unsigned short* __restrict__ Vt) {
    __shared__ float sA[2][32 * 68];   // 17 KB total, +4 pad keeps 16B align, rotates banks

    const int tid = threadIdx.x;
    const int wv  = tid >> 6;
    const int l   = tid & 63;
    const int wm  = wv >> 2;        // 0..1 row slab
    const int wn  = wv & 3;         // 0..3 -> jt0 = wn*3
    const int lg  = l >> 4, ll = l & 15;

    const int row0 = blockIdx.x * 32;

    // coalesced staging coords: thread t loads ids[row0 + t/16][(t&15)*4 ..+3]
    const int srow = tid >> 4;          // 0..31
    const int scol = (tid & 15) * 4;    // 0..60
    const float* gsrc = ids + (size_t)(row0 + srow) * Csz + scol;

    const int afrow = wm * 16 + ll;     // A-fragment row for this lane

    f32x4 acc[3];
    acc[0] = acc[1] = acc[2] = (f32x4){0.f, 0.f, 0.f, 0.f};

    float4 st = *(const float4*)gsrc;   // chunk 0 staged in regs

    const unsigned short* bbase_p = wB + ((size_t)(wn * 3) * 64 + l) * 8;  // +ks*6144

    for (int c = 0; c < 16; ++c) {
        float* bufp = &sA[c & 1][0];
        *(float4*)&bufp[srow * 68 + scol] = st;              // ds_write staged chunk
        if (c < 15) st = *(const float4*)(gsrc + (c + 1) * 64);  // prefetch next chunk
        __syncthreads();                                     // chunk visible to all

        // B frags for ks = 2c, 2c+1 (L2-hot)
        const unsigned short* bp = bbase_p + (size_t)(2 * c) * 6144;
        short8v b00 = *(const short8v*)(bp);
        short8v b01 = *(const short8v*)(bp + 512);
        short8v b02 = *(const short8v*)(bp + 1024);
        short8v b10 = *(const short8v*)(bp + 6144);
        short8v b11 = *(const short8v*)(bp + 6144 + 512);
        short8v b12 = *(const short8v*)(bp + 6144 + 1024);

        // A frags from LDS: ks-local 0 at cols lg*8, ks-local 1 at cols 32+lg*8
        const float* ap = &bufp[afrow * 68 + lg * 8];
        float4 a00 = *(const float4*)(ap);
        float4 a01 = *(const float4*)(ap + 4);
        float4 a10 = *(const float4*)(ap + 32);
        float4 a11 = *(const float4*)(ap + 36);

        union { short8v s; unsigned int u[4]; } af0, af1;
        af0.u[0] = pk2bf(a00.x, a00.y); af0.u[1] = pk2bf(a00.z, a00.w);
        af0.u[2] = pk2bf(a01.x, a01.y); af0.u[3] = pk2bf(a01.z, a01.w);
        af1.u[0] = pk2bf(a10.x, a10.y); af1.u[1] = pk2bf(a10.z, a10.w);
        af1.u[2] = pk2bf(a11.x, a11.y); af1.u[3] = pk2bf(a11.z, a11.w);

        acc[0] = __builtin_amdgcn_mfma_f32_16x16x32_bf16(af0.s, b00, acc[0], 0, 0, 0);
        acc[1] = __builtin_amdgcn_mfma_f32_16x16x32_bf16(af0.s, b01, acc[1], 0, 0, 0);
        acc[2] = __builtin_amdgcn_mfma_f32_16x16x32_bf16(af0.s, b02, acc[2], 0, 0, 0);
        acc[0] = __builtin_amdgcn_mfma_f32_16x16x32_bf16(af1.s, b10, acc[0], 0, 0, 0);
        acc[1] = __builtin_amdgcn_mfma_f32_16x16x32_bf16(af1.s, b11, acc[1], 0, 0, 0);
        acc[2] = __builtin_amdgcn_mfma_f32_16x16x32_bf16(af1.s, b12, acc[2], 0, 0, 0);
    }

    const int crow0 = row0 + wm * 16 + lg * 4;
#pragma unroll
    for (int n = 0; n < 3; ++n) {
        const int jb = wn * 3 + n;              // 0..11
        const int j  = jb * 16 + ll;
        const float bj = bias[j];
        float v0 = acc[n][0] + bj, v1 = acc[n][1] + bj;
        float v2 = acc[n][2] + bj, v3 = acc[n][3] + bj;
        if (jb < 4) {                           // Q
            unsigned short* q = &Qb[(size_t)crow0 * HSsz + j];
            q[0] = (unsigned short)f2bf(v0); q[HSsz] = (unsigned short)f2bf(v1);
            q[2 * HSsz] = (unsigned short)f2bf(v2); q[3 * HSsz] = (unsigned short)f2bf(v3);
        } else if (jb < 8) {                    // K
            unsigned short* k = &Kb[(size_t)crow0 * HSsz + (j - 64)];
            k[0] = (unsigned short)f2bf(v0); k[HSsz] = (unsigned short)f2bf(v1);
            k[2 * HSsz] = (unsigned short)f2bf(v2); k[3 * HSsz] = (unsigned short)f2bf(v3);
        } else {                                // V -> Vt[b][d][t]
            int d = j - 128;
            uint2 pk;
            pk.x = f2bf(v0) | (f2bf(v1) << 16);
            pk.y = f2bf(v2) | (f2bf(v3) << 16);
            *(uint2*)&Vt[((size_t)(crow0 >> 11) * HSsz + d) * Tsz + (crow0 & 2047)] = pk;
        }
    }
}

// ---------------- fused causal attention via bf16 MFMA (no softmax) ----------------
__global__ __launch_bounds__(256) void k_attn_mfma(const unsigned short* __restrict__ Qb,
                                                   const unsigned short* __restrict__ Kb,
                                                   const unsigned short* __restrict__ Vt,
                                                   unsigned short* __restrict__ hb) {
    __shared__ __align__(16) unsigned int s_su[4][576];   // per-wave S tile [16][72] bf16
    __shared__ float s_o[4][1024];                         // per-wave partial O [16][64]

    const int tid = threadIdx.x;
    const int w  = tid >> 6;
    const int l  = tid & 63;
    const int lg = l >> 4;
    const int ll = l & 15;

    const int u = blockIdx.x;
    const int b = u / 96;
    const int r = u - b * 96;

    int si, sub, nsub;
    const bool heavy = (r < 64);
    if (heavy) { si = 64 + r; sub = w; nsub = 4; }
    else {
        int rr = r - 64;
        si = (w < 2) ? (63 - rr) : rr;
        sub = w & 1; nsub = 2;
    }
    const int nT  = (si >> 2) + 1;
    const int qn  = nT / nsub, rem = nT % nsub;
    const int t0  = sub * qn + (sub < rem ? sub : rem);
    const int cnt = qn + (sub < rem ? 1 : 0);

    const int q0 = si * 16;
    const int bbase = b * Tsz;

    short8v qf0, qf1;
    {
        const unsigned short* qp = Qb + (size_t)(bbase + q0 + ll) * HSsz + lg * 8;
        qf0 = *(const short8v*)qp;
        qf1 = *(const short8v*)(qp + 32);
    }

    f32x4 oacc[4];
#pragma unroll
    for (int n = 0; n < 4; ++n) oacc[n] = (f32x4){0.f, 0.f, 0.f, 0.f};

    for (int tile = t0; tile < t0 + cnt; ++tile) {
        const int s0 = tile * 64;
        const unsigned short* kp = Kb + (size_t)(bbase + s0 + ll) * HSsz + lg * 8;
        f32x4 sacc[4];
#pragma unroll
        for (int m = 0; m < 4; ++m) sacc[m] = (f32x4){0.f, 0.f, 0.f, 0.f};
#pragma unroll
        for (int m = 0; m < 4; ++m) {
            short8v k0 = *(const short8v*)(kp + m * 16 * HSsz);
            short8v k1 = *(const short8v*)(kp + m * 16 * HSsz + 32);
            sacc[m] = __builtin_amdgcn_mfma_f32_16x16x32_bf16(k0, qf0, sacc[m], 0, 0, 0);
            sacc[m] = __builtin_amdgcn_mfma_f32_16x16x32_bf16(k1, qf1, sacc[m], 0, 0, 0);
        }
        if (tile == nT - 1) {
            const int tg = q0 + ll;
#pragma unroll
            for (int m = 0; m < 4; ++m)
#pragma unroll
                for (int rr2 = 0; rr2 < 4; ++rr2) {
                    int sg = s0 + 16 * m + 4 * lg + rr2;
                    if (sg > tg) sacc[m][rr2] = 0.f;
                }
        }
#pragma unroll
        for (int m = 0; m < 4; ++m) {
            uint2 pk;
            pk.x = f2bf(sacc[m][0]) | (f2bf(sacc[m][1]) << 16);
            pk.y = f2bf(sacc[m][2]) | (f2bf(sacc[m][3]) << 16);
            *(uint2*)&s_su[w][ll * 36 + 8 * m + 2 * lg] = pk;
        }
        union { uint4 u4; short8v s; } a0, a1;
        a0.u4 = *(const uint4*)&s_su[w][ll * 36 + 4 * lg];
        a1.u4 = *(const uint4*)&s_su[w][ll * 36 + 16 + 4 * lg];
        const unsigned short* vp = Vt + (size_t)(b * HSsz + ll) * Tsz + s0 + lg * 8;
#pragma unroll
        for (int n = 0; n < 4; ++n) {
            short8v v0 = *(const short8v*)(vp + n * 16 * Tsz);
            short8v v1 = *(const short8v*)(vp + n * 16 * Tsz + 32);
            oacc[n] = __builtin_amdgcn_mfma_f32_16x16x32_bf16(a0.s, v0, oacc[n], 0, 0, 0);
            oacc[n] = __builtin_amdgcn_mfma_f32_16x16x32_bf16(a1.s, v1, oacc[n], 0, 0, 0);
        }
    }

#pragma unroll
    for (int n = 0; n < 4; ++n)
#pragma unroll
        for (int rr2 = 0; rr2 < 4; ++rr2)
            s_o[w][(4 * lg + rr2) * 64 + 16 * n + ll] = oacc[n][rr2];
    __syncthreads();

    if (heavy) {
        const int e = tid * 4;
        float4 v = *(const float4*)&s_o[0][e];
        const float4 v1 = *(const float4*)&s_o[1][e];
        const float4 v2 = *(const float4*)&s_o[2][e];
        const float4 v3 = *(const float4*)&s_o[3][e];
        v.x += v1.x + v2.x + v3.x; v.y += v1.y + v2.y + v3.y;
        v.z += v1.z + v2.z + v3.z; v.w += v1.w + v2.w + v3.w;
        const int t = e >> 6, d = e & 63;
        uint2 pk;
        pk.x = f2bf(v.x) | (f2bf(v.y) << 16);
        pk.y = f2bf(v.z) | (f2bf(v.w) << 16);
        *(uint2*)&hb[(size_t)(bbase + q0 + t) * HSsz + d] = pk;
    } else {
        const int half = tid >> 7;
        const int tt2 = tid & 127;
        const int e = tt2 * 8;
        const int rr = r - 64;
        const int sih = half ? rr : (63 - rr);
        float4 x0 = *(const float4*)&s_o[2 * half][e];
        float4 y0 = *(const float4*)&s_o[2 * half + 1][e];
        float4 x1 = *(const float4*)&s_o[2 * half][e + 4];
        float4 y1 = *(const float4*)&s_o[2 * half + 1][e + 4];
        x0.x += y0.x; x0.y += y0.y; x0.z += y0.z; x0.w += y0.w;
        x1.x += y1.x; x1.y += y1.y; x1.z += y1.z; x1.w += y1.w;
        const int t = e >> 6, d = e & 63;
        uint4 pk;
        pk.x = f2bf(x0.x) | (f2bf(x0.y) << 16);
        pk.y = f2bf(x0.z) | (f2bf(x0.w) << 16);
        pk.z = f2bf(x1.x) | (f2bf(x1.y) << 16);
        pk.w = f2bf(x1.z) | (f2bf(x1.w) << 16);
        *(uint4*)&hb[(size_t)(bbase + sih * 16 + t) * HSsz + d] = pk;
    }
}

// ---------------- out = h @ W2^T + pb via swapped-operand MFMA ----------------
__global__ __launch_bounds__(256) void k_proj_mfma(const unsigned short* __restrict__ h,
                                                   const unsigned short* __restrict__ w2a,
                                                   const float* __restrict__ pb,
                                                   float* __restrict__ out) {
    const int tid = threadIdx.x;
    const int w = tid >> 6, l = tid & 63;
    const int t0 = blockIdx.x * 16;

    const unsigned short* hp = h + (size_t)(t0 + (l & 15)) * HSsz + (l >> 4) * 8;
    short8v hb0 = *(const short8v*)hp;          // d = 0..31 slice
    short8v hb1 = *(const short8v*)(hp + 32);   // d = 32..63 slice

    const int row = (l >> 4) * 4;
    const int tcol = l & 15;
    const size_t outrow = (size_t)(t0 + tcol) * Csz;

#pragma unroll 2
    for (int m = w * 16; m < w * 16 + 16; ++m) {
        const unsigned short* ap = w2a + (size_t)(m * 64 + l) * 8;
        short8v a0 = *(const short8v*)ap;
        short8v a1 = *(const short8v*)(ap + 32768);   // ks=1 plane: 64*64*8
        f32x4 acc = (f32x4){0.f, 0.f, 0.f, 0.f};
        acc = __builtin_amdgcn_mfma_f32_16x16x32_bf16(a0, hb0, acc, 0, 0, 0);
        acc = __builtin_amdgcn_mfma_f32_16x16x32_bf16(a1, hb1, acc, 0, 0, 0);
        const int c0 = m * 16 + row;
        const float4 pv = *(const float4*)&pb[c0];
        float4 o;
        o.x = acc[0] + pv.x; o.y = acc[1] + pv.y;
        o.z = acc[2] + pv.z; o.w = acc[3] + pv.w;
        *(float4*)&out[outrow + c0] = o;
    }
}

extern "C" void kernel_launch(void* const* d_in, const int* in_sizes, int n_in,
                              void* d_out, int out_size, void* d_ws, size_t ws_size,
                              hipStream_t stream) {
    const float* ids    = (const float*)d_in[0];
    const float* qkv_w  = (const float*)d_in[1];
    const float* qkv_b  = (const float*)d_in[2];
    const float* proj_w = (const float*)d_in[3];
    const float* proj_b = (const float*)d_in[4];
    float* out = (float*)d_out;

    unsigned short* Qb  = (unsigned short*)d_ws;       // 2 MB
    unsigned short* Kb  = Qb + 16384 * HSsz;           // 2 MB
    unsigned short* Vt  = Kb + 16384 * HSsz;           // 2 MB ([b][d][t])
    unsigned short* hb  = Vt + 16384 * HSsz;           // 2 MB (bf16 h)
    unsigned short* wB  = hb + 16384 * HSsz;           // 384 KB
    unsigned short* w2a = wB + 196608;                 // 128 KB

    hipLaunchKernelGGL(k_prep,      dim3(128),  dim3(256), 0, stream, qkv_w, proj_w, wB, w2a);
    hipLaunchKernelGGL(k_qkv_mfma,  dim3(512),  dim3(512), 0, stream, ids, wB, qkv_b, Qb, Kb, Vt);
    hipLaunchKernelGGL(k_attn_mfma, dim3(768),  dim3(256), 0, stream, Qb, Kb, Vt, hb);
    hipLaunchKernelGGL(k_proj_mfma, dim3(1024), dim3(256), 0, stream, hb, w2a, proj_b, out);
}

// Round 6
// 62.813 us; speedup vs baseline: 6.0931x; 1.3315x over previous
//
#include <hip/hip_runtime.h>
#include <hip/hip_bf16.h>

#define Bsz 8
#define Tsz 2048
#define Csz 1024
#define HSsz 64
#define NQ 192   // 3*hs

typedef __attribute__((ext_vector_type(8))) short short8v;
typedef __attribute__((ext_vector_type(4))) float f32x4;
typedef unsigned short ushortT;
typedef unsigned int uintT;

// fp32 -> bf16 round-to-nearest-even (bit pattern)
__device__ __forceinline__ unsigned int f2bf(float f) {
    union { float f; unsigned int u; } v; v.f = f;
    return (v.u + 0x7fffu + ((v.u >> 16) & 1u)) >> 16;
}

__device__ __forceinline__ unsigned int pk2bf(float lo, float hi) {
    union { __hip_bfloat162 h2; unsigned int u; } cv;
    cv.h2 = __float22bfloat162_rn(float2{lo, hi});
    return cv.u;
}

// ------------- prep: pack qkv_w B-frags (blocks 0..95) + W2 A-frags (blocks 96..127) -------------
__global__ __launch_bounds__(256) void k_prep(const float* __restrict__ qw,
                                              const float* __restrict__ pw,
                                              ushortT* __restrict__ wB,
                                              ushortT* __restrict__ w2a) {
    const int blk = blockIdx.x;
    if (blk < 96) {
        int idx = blk * 256 + threadIdx.x;      // 24576 threads = 32ks*12jt*64l
        int l = idx & 63;
        int ksjt = idx >> 6;
        int jt = ksjt % 12, ks = ksjt / 12;
        int j = jt * 16 + (l & 15);
        int k = ks * 32 + (l >> 4) * 8;
        const float* src = &qw[j * Csz + k];
        float4 a = *(const float4*)src;
        float4 b = *(const float4*)(src + 4);
        uint4 o;
        o.x = f2bf(a.x) | (f2bf(a.y) << 16);
        o.y = f2bf(a.z) | (f2bf(a.w) << 16);
        o.z = f2bf(b.x) | (f2bf(b.y) << 16);
        o.w = f2bf(b.z) | (f2bf(b.w) << 16);
        *(uint4*)&wB[(size_t)idx * 8] = o;
    } else {
        int idx = (blk - 96) * 256 + threadIdx.x;   // 0..8191 = 2ks*64m*64l
        int l = idx & 63;
        int rest = idx >> 6;
        int m = rest & 63, ks = rest >> 6;
        int c = m * 16 + (l & 15);
        int d0 = ks * 32 + (l >> 4) * 8;
        float s0 = 0, s1 = 0, s2 = 0, s3 = 0, s4 = 0, s5 = 0, s6 = 0, s7 = 0;
#pragma unroll
        for (int hh = 0; hh < 16; ++hh) {
            const float* p = &pw[c * Csz + hh * HSsz + d0];
            float4 x = *(const float4*)p;
            float4 y = *(const float4*)(p + 4);
            s0 += x.x; s1 += x.y; s2 += x.z; s3 += x.w;
            s4 += y.x; s5 += y.y; s6 += y.z; s7 += y.w;
        }
        uint4 o;
        o.x = f2bf(s0) | (f2bf(s1) << 16);
        o.y = f2bf(s2) | (f2bf(s3) << 16);
        o.z = f2bf(s4) | (f2bf(s5) << 16);
        o.w = f2bf(s6) | (f2bf(s7) << 16);
        *(uint4*)&w2a[(size_t)idx * 8] = o;
    }
}

// ---------------- qkv GEMM via bf16 MFMA, LDS-staged A; emits fragment-packed Qf/Kf/Vf ----
// 512 thr = 8 waves: wm(2 row-slabs) x wn(4 col-groups of 48). Block tile 32x192.
// Qf/Kf: [(M16*2+ks)*64+l][8] = X[M16*16 + (l&15)][ks*32 + (l>>4)*8 + b]
// Vf:    [((b*64+s32)*4+n)*64+l][8] = V[s32*32 + (l>>4)*8 + b][16n + (l&15)]
__global__ __launch_bounds__(512, 4) void k_qkv_mfma(const float* __restrict__ ids,
                                                     const ushortT* __restrict__ wB,
                                                     const float* __restrict__ bias,
                                                     ushortT* __restrict__ Qf,
                                                     ushortT* __restrict__ Kf,
                                                     ushortT* __restrict__ Vf) {
    __shared__ float sA[2][32 * 68];   // staging; epilogue overlays Lqk/Lv here
    uintT* Lqk = (uintT*)&sA[0][0];    // [32 t][68 uint]  (ushort view [32][136], j 0..127)
    uintT* Lv  = Lqk + 32 * 68;        // [64 d][20 uint]  (t-pairs)

    const int tid = threadIdx.x;
    const int wv  = tid >> 6;
    const int l   = tid & 63;
    const int wm  = wv >> 2;        // 0..1 row slab
    const int wn  = wv & 3;         // 0..3 -> jt0 = wn*3
    const int lg  = l >> 4, ll = l & 15;

    const int row0 = blockIdx.x * 32;

    const int srow = tid >> 4;          // 0..31
    const int scol = (tid & 15) * 4;    // 0..60
    const float* gsrc = ids + (size_t)(row0 + srow) * Csz + scol;

    const int afrow = wm * 16 + ll;

    f32x4 acc[3];
    acc[0] = acc[1] = acc[2] = (f32x4){0.f, 0.f, 0.f, 0.f};

    float4 st = *(const float4*)gsrc;

    const ushortT* bbase_p = wB + ((size_t)(wn * 3) * 64 + l) * 8;

    for (int c = 0; c < 16; ++c) {
        float* bufp = &sA[c & 1][0];
        *(float4*)&bufp[srow * 68 + scol] = st;
        if (c < 15) st = *(const float4*)(gsrc + (c + 1) * 64);
        __syncthreads();

        const ushortT* bp = bbase_p + (size_t)(2 * c) * 6144;
        short8v b00 = *(const short8v*)(bp);
        short8v b01 = *(const short8v*)(bp + 512);
        short8v b02 = *(const short8v*)(bp + 1024);
        short8v b10 = *(const short8v*)(bp + 6144);
        short8v b11 = *(const short8v*)(bp + 6144 + 512);
        short8v b12 = *(const short8v*)(bp + 6144 + 1024);

        const float* ap = &bufp[afrow * 68 + lg * 8];
        float4 a00 = *(const float4*)(ap);
        float4 a01 = *(const float4*)(ap + 4);
        float4 a10 = *(const float4*)(ap + 32);
        float4 a11 = *(const float4*)(ap + 36);

        union { short8v s; unsigned int u[4]; } af0, af1;
        af0.u[0] = pk2bf(a00.x, a00.y); af0.u[1] = pk2bf(a00.z, a00.w);
        af0.u[2] = pk2bf(a01.x, a01.y); af0.u[3] = pk2bf(a01.z, a01.w);
        af1.u[0] = pk2bf(a10.x, a10.y); af1.u[1] = pk2bf(a10.z, a10.w);
        af1.u[2] = pk2bf(a11.x, a11.y); af1.u[3] = pk2bf(a11.z, a11.w);

        acc[0] = __builtin_amdgcn_mfma_f32_16x16x32_bf16(af0.s, b00, acc[0], 0, 0, 0);
        acc[1] = __builtin_amdgcn_mfma_f32_16x16x32_bf16(af0.s, b01, acc[1], 0, 0, 0);
        acc[2] = __builtin_amdgcn_mfma_f32_16x16x32_bf16(af0.s, b02, acc[2], 0, 0, 0);
        acc[0] = __builtin_amdgcn_mfma_f32_16x16x32_bf16(af1.s, b10, acc[0], 0, 0, 0);
        acc[1] = __builtin_amdgcn_mfma_f32_16x16x32_bf16(af1.s, b11, acc[1], 0, 0, 0);
        acc[2] = __builtin_amdgcn_mfma_f32_16x16x32_bf16(af1.s, b12, acc[2], 0, 0, 0);

        __syncthreads();   // protect sA buffer reuse (2-deep rotation is tight)
    }

    // ---- epilogue: transpose through LDS, emit fragment-packed outputs ----
    const int crow_l = wm * 16 + lg * 4;    // local t row (base of 4)
    ushortT* L16 = (ushortT*)Lqk;
#pragma unroll
    for (int n = 0; n < 3; ++n) {
        const int jb = wn * 3 + n;
        const int j  = jb * 16 + ll;
        const float bj = bias[j];
        float v0 = acc[n][0] + bj, v1 = acc[n][1] + bj;
        float v2 = acc[n][2] + bj, v3 = acc[n][3] + bj;
        if (jb < 8) {   // Q (j 0..63) and K (j 64..127): write along t
            ushortT* p = &L16[crow_l * 136 + j];
            p[0]   = (ushortT)f2bf(v0);
            p[136] = (ushortT)f2bf(v1);
            p[272] = (ushortT)f2bf(v2);
            p[408] = (ushortT)f2bf(v3);
        } else {        // V: d-major, t-pairs
            uintT* p = &Lv[(j - 128) * 20 + (crow_l >> 1)];
            p[0] = pk2bf(v0, v1);
            p[1] = pk2bf(v2, v3);
        }
    }
    __syncthreads();

    const int l2 = tid & 63, ll2 = l2 & 15, lg2 = l2 >> 4;
    if (tid < 256) {
        const int ks = (tid >> 6) & 1, m = tid >> 7;
        uint4 q = *(const uint4*)&Lqk[(m * 16 + ll2) * 68 + ks * 16 + lg2 * 4];
        *(uint4*)&Qf[(((size_t)(row0 >> 4) + m) * 2 + ks) * 512 + l2 * 8] = q;
        const int n = tid >> 6;     // 0..3
        uint4 v = *(const uint4*)&Lv[(n * 16 + ll2) * 20 + lg2 * 4];
        const int bb = row0 >> 11, s32 = (row0 >> 5) & 63;
        *(uint4*)&Vf[((((size_t)bb * 64 + s32) * 4 + n) * 64 + l2) * 8] = v;
    } else {
        const int ks = (tid >> 6) & 1, m = (tid >> 7) & 1;
        uint4 k = *(const uint4*)&Lqk[(m * 16 + ll2) * 68 + 32 + ks * 16 + lg2 * 4];
        *(uint4*)&Kf[(((size_t)(row0 >> 4) + m) * 2 + ks) * 512 + l2 * 8] = k;
    }
}

// ---------------- fused causal attention via bf16 MFMA (no softmax) ----------------
// 32 q-rows per wave. Heavy block (r<32): strip si=63-r, 4-way tile split.
// Light block: strips (31-rr, rr) — constant 17 tiles — each 2-way split.
// All frag loads coalesced from packed Qf/Kf/Vf; swapped QK^T; per-wave S bounce.
__global__ __launch_bounds__(256, 3) void k_attn_mfma(const ushortT* __restrict__ Qf,
                                                      const ushortT* __restrict__ Kf,
                                                      const ushortT* __restrict__ Vf,
                                                      ushortT* __restrict__ hf) {
    __shared__ uintT su[4 * 2 * 16 * 36];   // per-wave S^T bounce, 18.4 KB
    __shared__ float s_o[4][32 * 68];       // per-wave partial O, padded, 34.8 KB

    const int tid = threadIdx.x;
    const int w  = tid >> 6;
    const int l  = tid & 63;
    const int lg = l >> 4;
    const int ll = l & 15;

    const int u = blockIdx.x;
    const int b = u / 48;
    const int r = u - b * 48;

    int si, sub, nsub;
    const bool heavy = (r < 32);
    if (heavy) { si = 63 - r; sub = w; nsub = 4; }
    else {
        const int rr = r - 32;
        si = (w < 2) ? (31 - rr) : rr;
        sub = w & 1; nsub = 2;
    }
    const int nT  = (si >> 1) + 1;          // 64-key tiles for this strip
    const int qn  = nT / nsub, rem = nT % nsub;
    const int t0  = sub * qn + (sub < rem ? sub : rem);
    const int cnt = qn + (sub < rem ? 1 : 0);

    const int gq = b * 128 + si * 2;        // global 16-row group of first q rows

    short8v qf[2][2];
#pragma unroll
    for (int mt = 0; mt < 2; ++mt)
#pragma unroll
        for (int ks = 0; ks < 2; ++ks)
            qf[mt][ks] = *(const short8v*)&Qf[(((size_t)gq + mt) * 2 + ks) * 512 + l * 8];

    f32x4 oacc[2][4];
#pragma unroll
    for (int mt = 0; mt < 2; ++mt)
#pragma unroll
        for (int n = 0; n < 4; ++n) oacc[mt][n] = (f32x4){0.f, 0.f, 0.f, 0.f};

    for (int tile = t0; tile < t0 + cnt; ++tile) {
        const int gs = b * 128 + tile * 4;
        short8v kf[4][2];
#pragma unroll
        for (int ms = 0; ms < 4; ++ms) {
            const ushortT* kp = &Kf[(((size_t)gs + ms) * 2) * 512 + l * 8];
            kf[ms][0] = *(const short8v*)kp;
            kf[ms][1] = *(const short8v*)(kp + 512);
        }
        f32x4 sacc[4][2];
#pragma unroll
        for (int ms = 0; ms < 4; ++ms)
#pragma unroll
            for (int mt = 0; mt < 2; ++mt) sacc[ms][mt] = (f32x4){0.f, 0.f, 0.f, 0.f};
#pragma unroll
        for (int ms = 0; ms < 4; ++ms)
#pragma unroll
            for (int mt = 0; mt < 2; ++mt) {
                sacc[ms][mt] = __builtin_amdgcn_mfma_f32_16x16x32_bf16(kf[ms][0], qf[mt][0], sacc[ms][mt], 0, 0, 0);
                sacc[ms][mt] = __builtin_amdgcn_mfma_f32_16x16x32_bf16(kf[ms][1], qf[mt][1], sacc[ms][mt], 0, 0, 0);
            }
        if (tile == nT - 1) {   // causal mask on diagonal tile
#pragma unroll
            for (int ms = 0; ms < 4; ++ms)
#pragma unroll
                for (int mt = 0; mt < 2; ++mt) {
                    const int tg = si * 32 + mt * 16 + ll;
#pragma unroll
                    for (int rr2 = 0; rr2 < 4; ++rr2) {
                        int sg = tile * 64 + ms * 16 + 4 * lg + rr2;
                        if (sg > tg) sacc[ms][mt][rr2] = 0.f;
                    }
                }
        }
        // bounce S^T -> bf16 A-frags (per-wave LDS, no barrier)
#pragma unroll
        for (int mt = 0; mt < 2; ++mt)
#pragma unroll
            for (int ms = 0; ms < 4; ++ms) {
                uint2 pk;
                pk.x = pk2bf(sacc[ms][mt][0], sacc[ms][mt][1]);
                pk.y = pk2bf(sacc[ms][mt][2], sacc[ms][mt][3]);
                *(uint2*)&su[((w * 2 + mt) * 16 + ll) * 36 + ms * 8 + 2 * lg] = pk;
            }
        union { uint4 u4; short8v s; } pa[2][2];
#pragma unroll
        for (int mt = 0; mt < 2; ++mt)
#pragma unroll
            for (int h = 0; h < 2; ++h)
                pa[mt][h].u4 = *(const uint4*)&su[((w * 2 + mt) * 16 + ll) * 36 + h * 16 + lg * 4];

        const int gv = b * 64 + tile * 2;
        short8v vf[2][4];
#pragma unroll
        for (int h = 0; h < 2; ++h)
#pragma unroll
            for (int n = 0; n < 4; ++n)
                vf[h][n] = *(const short8v*)&Vf[((((size_t)gv + h) * 4 + n) * 64 + l) * 8];
#pragma unroll
        for (int mt = 0; mt < 2; ++mt)
#pragma unroll
            for (int n = 0; n < 4; ++n) {
                oacc[mt][n] = __builtin_amdgcn_mfma_f32_16x16x32_bf16(pa[mt][0].s, vf[0][n], oacc[mt][n], 0, 0, 0);
                oacc[mt][n] = __builtin_amdgcn_mfma_f32_16x16x32_bf16(pa[mt][1].s, vf[1][n], oacc[mt][n], 0, 0, 0);
            }
    }

    // partial O to LDS
#pragma unroll
    for (int mt = 0; mt < 2; ++mt)
#pragma unroll
        for (int n = 0; n < 4; ++n)
#pragma unroll
            for (int rr2 = 0; rr2 < 4; ++rr2)
                s_o[w][(mt * 16 + 4 * lg + rr2) * 68 + 16 * n + ll] = oacc[mt][n][rr2];
    __syncthreads();

    // combine + emit fragment-packed hf
    const int l2 = tid & 63, ll2 = l2 & 15, lg2 = l2 >> 4;
    const int ks = (tid >> 6) & 1, mt = tid >> 7;
    const int t = mt * 16 + ll2, dd = ks * 32 + lg2 * 8;
    if (heavy) {
        float4 A = {0, 0, 0, 0}, B2 = {0, 0, 0, 0};
#pragma unroll
        for (int w2 = 0; w2 < 4; ++w2) {
            const float4 x = *(const float4*)&s_o[w2][t * 68 + dd];
            const float4 y = *(const float4*)&s_o[w2][t * 68 + dd + 4];
            A.x += x.x; A.y += x.y; A.z += x.z; A.w += x.w;
            B2.x += y.x; B2.y += y.y; B2.z += y.z; B2.w += y.w;
        }
        uint4 o;
        o.x = pk2bf(A.x, A.y);  o.y = pk2bf(A.z, A.w);
        o.z = pk2bf(B2.x, B2.y); o.w = pk2bf(B2.z, B2.w);
        *(uint4*)&hf[(((size_t)(b * 128 + si * 2) + mt) * 2 + ks) * 512 + l2 * 8] = o;
    } else {
        const int rr = r - 32;
        const int sa = 31 - rr, sb = rr;
        float4 A = {0, 0, 0, 0}, B2 = {0, 0, 0, 0};
#pragma unroll
        for (int w2 = 0; w2 < 2; ++w2) {
            const float4 x = *(const float4*)&s_o[w2][t * 68 + dd];
            const float4 y = *(const float4*)&s_o[w2][t * 68 + dd + 4];
            A.x += x.x; A.y += x.y; A.z += x.z; A.w += x.w;
            B2.x += y.x; B2.y += y.y; B2.z += y.z; B2.w += y.w;
        }
        uint4 o;
        o.x = pk2bf(A.x, A.y);  o.y = pk2bf(A.z, A.w);
        o.z = pk2bf(B2.x, B2.y); o.w = pk2bf(B2.z, B2.w);
        *(uint4*)&hf[(((size_t)(b * 128 + sa * 2) + mt) * 2 + ks) * 512 + l2 * 8] = o;
        float4 C = {0, 0, 0, 0}, D2 = {0, 0, 0, 0};
#pragma unroll
        for (int w2 = 2; w2 < 4; ++w2) {
            const float4 x = *(const float4*)&s_o[w2][t * 68 + dd];
            const float4 y = *(const float4*)&s_o[w2][t * 68 + dd + 4];
            C.x += x.x; C.y += x.y; C.z += x.z; C.w += x.w;
            D2.x += y.x; D2.y += y.y; D2.z += y.z; D2.w += y.w;
        }
        uint4 o2;
        o2.x = pk2bf(C.x, C.y);  o2.y = pk2bf(C.z, C.w);
        o2.z = pk2bf(D2.x, D2.y); o2.w = pk2bf(D2.z, D2.w);
        *(uint4*)&hf[(((size_t)(b * 128 + sb * 2) + mt) * 2 + ks) * 512 + l2 * 8] = o2;
    }
}

// ---------------- out = h @ W2^T + pb via swapped-operand MFMA ----------------
// hf is fragment-packed: B-frag load is one coalesced dwordx4 per k-half.
__global__ __launch_bounds__(256) void k_proj_mfma(const ushortT* __restrict__ hf,
                                                   const ushortT* __restrict__ w2a,
                                                   const float* __restrict__ pb,
                                                   float* __restrict__ out) {
    const int tid = threadIdx.x;
    const int w = tid >> 6, l = tid & 63;
    const int t0 = blockIdx.x * 16;
    const size_t M = blockIdx.x;

    short8v hb0 = *(const short8v*)&hf[(M * 2 + 0) * 512 + l * 8];
    short8v hb1 = *(const short8v*)&hf[(M * 2 + 1) * 512 + l * 8];

    const int row = (l >> 4) * 4;
    const int tcol = l & 15;
    const size_t outrow = (size_t)(t0 + tcol) * Csz;

#pragma unroll 2
    for (int m = w * 16; m < w * 16 + 16; ++m) {
        const ushortT* ap = w2a + (size_t)(m * 64 + l) * 8;
        short8v a0 = *(const short8v*)ap;
        short8v a1 = *(const short8v*)(ap + 32768);   // ks=1 plane: 64*64*8
        f32x4 acc = (f32x4){0.f, 0.f, 0.f, 0.f};
        acc = __builtin_amdgcn_mfma_f32_16x16x32_bf16(a0, hb0, acc, 0, 0, 0);
        acc = __builtin_amdgcn_mfma_f32_16x16x32_bf16(a1, hb1, acc, 0, 0, 0);
        const int c0 = m * 16 + row;
        const float4 pv = *(const float4*)&pb[c0];
        float4 o;
        o.x = acc[0] + pv.x; o.y = acc[1] + pv.y;
        o.z = acc[2] + pv.z; o.w = acc[3] + pv.w;
        *(float4*)&out[outrow + c0] = o;
    }
}

extern "C" void kernel_launch(void* const* d_in, const int* in_sizes, int n_in,
                              void* d_out, int out_size, void* d_ws, size_t ws_size,
                              hipStream_t stream) {
    const float* ids    = (const float*)d_in[0];
    const float* qkv_w  = (const float*)d_in[1];
    const float* qkv_b  = (const float*)d_in[2];
    const float* proj_w = (const float*)d_in[3];
    const float* proj_b = (const float*)d_in[4];
    float* out = (float*)d_out;

    ushortT* Qf  = (ushortT*)d_ws;          // 2 MB fragment-packed
    ushortT* Kf  = Qf + 16384 * HSsz;       // 2 MB
    ushortT* Vf  = Kf + 16384 * HSsz;       // 2 MB
    ushortT* hf  = Vf + 16384 * HSsz;       // 2 MB
    ushortT* wB  = hf + 16384 * HSsz;       // 384 KB
    ushortT* w2a = wB + 196608;             // 128 KB

    hipLaunchKernelGGL(k_prep,      dim3(128),  dim3(256), 0, stream, qkv_w, proj_w, wB, w2a);
    hipLaunchKernelGGL(k_qkv_mfma,  dim3(512),  dim3(512), 0, stream, ids, wB, qkv_b, Qf, Kf, Vf);
    hipLaunchKernelGGL(k_attn_mfma, dim3(384),  dim3(256), 0, stream, Qf, Kf, Vf, hf);
    hipLaunchKernelGGL(k_proj_mfma, dim3(1024), dim3(256), 0, stream, hf, w2a, proj_b, out);
}